// Round 14
// baseline (700.683 us; speedup 1.0000x reference)
//
#include <hip/hip_runtime.h>
#include <cstdint>
#include <cstddef>

#define HIDC 128
#define NHEAD 8
#define NLAY 3
#define NGRAPH 64
#define NCLS 3
#define MAXI 6   // fast path deg <= 48

typedef __attribute__((ext_vector_type(8))) short short8;
typedef __attribute__((ext_vector_type(4))) float floatx4;
typedef __attribute__((ext_vector_type(2))) float floatx2;

__device__ inline short f2bf(float x) {
  unsigned u = __float_as_uint(x);
  unsigned r = (u + 0x7fff + ((u >> 16) & 1)) >> 16;   // RNE
  return (short)r;
}
__device__ inline float bf2f(unsigned short u) {
  return __uint_as_float(((unsigned)u) << 16);
}

// ---------------------------------------------------------------------------
// B matrices are stored in MFMA-FRAGMENT order:
//   Bf[frag*512 + lane*8 + j]  ==  B[col16*16 + (lane&15)][kb64*64 + kk*32 + (lane>>4)*8 + j]
//   frag = (col16 * (K/64) + kb64) * 2 + kk
// so each wave's B operand is ONE contiguous 1KB coalesced load.
//
// The agg matrix (A of the 3 GAT-layer GEMMs) is stored K-TILED:
//   aggT[rb][kb64][rr][ko]  ==  A[rb*128 + rr][kb64*64 + ko]   (rr<128, ko<64)
// so each block-step of mm_gat reads ONE contiguous 16KB chunk (full DRAM
// pages, stream-prefetch friendly) instead of 128B column-slices at 2KB
// stride.
// ---------------------------------------------------------------------------

// ---------------------------------------------------------------------------
// Unified prep kernel: encT/Wp/Bt512 built in fragment order, waSD dots,
// d_out + cnt zeroing.
// ---------------------------------------------------------------------------
__global__ __launch_bounds__(256) void prep_kernel(
    const float* __restrict__ enc_W, short* __restrict__ encT,
    const float* __restrict__ gat_W, short* __restrict__ Wp,
    const float* __restrict__ W_ih, const float* __restrict__ W_hh,
    short* __restrict__ Bt512,
    const float* __restrict__ att_src, const float* __restrict__ att_dst,
    float* __restrict__ waSD,
    float* __restrict__ d_out_f, int out_size, float* __restrict__ cnt)
{
  int idx = blockIdx.x * 256 + threadIdx.x;

  // encT: K=128, 8 col16 x 2 kb64 x 2 kk = 32 frags x 512 shorts
  if (idx < 16384) {
    int frag = idx >> 9, rem = idx & 511;
    int lane = rem >> 3, j = rem & 7;
    int col16 = frag >> 2, kb64 = (frag >> 1) & 1, kk = frag & 1;
    int col = col16 * 16 + (lane & 15);
    int k = kb64 * 64 + kk * 32 + ((lane >> 4) << 3) + j;
    encT[idx] = f2bf(enc_W[(size_t)k * 128 + col]);
    return;
  }
  idx -= 16384;

  // Wp: per layer K=1024, 8 col16 x 16 kb64 x 2 kk = 256 frags x 512 shorts
  if (idx < NLAY * 131072) {
    int l = idx >> 17, rem17 = idx & 131071;
    int frag = rem17 >> 9, rem = rem17 & 511;
    int lane = rem >> 3, j = rem & 7;
    int col16 = frag >> 5, kb64 = (frag >> 1) & 15, kk = frag & 1;
    int cc = col16 * 16 + (lane & 15);
    int k1024 = kb64 * 64 + kk * 32 + ((lane >> 4) << 3) + j;
    int hh = k1024 >> 7, k = k1024 & 127;
    Wp[idx] = f2bf(gat_W[(size_t)l * 131072 + (size_t)k * 1024 + hh * 128 + cc]
                   * 0.125f);
    return;
  }
  idx -= NLAY * 131072;

  // Bt512: K=256, 32 col16 x 4 kb64 x 2 kk = 256 frags x 512 shorts
  if (idx < 512 * 256) {
    int frag = idx >> 9, rem = idx & 511;
    int lane = rem >> 3, j = rem & 7;
    int col16 = frag >> 3, kb64 = (frag >> 1) & 3, kk = frag & 1;
    int col = col16 * 16 + (lane & 15);
    int k = kb64 * 64 + kk * 32 + ((lane >> 4) << 3) + j;
    float v;
    if (k < 128) {
      v = (col < 384) ? W_ih[(size_t)col * 128 + k] : 0.f;
    } else {
      int k2 = k - 128;
      if (col < 256) v = W_hh[(size_t)col * 128 + k2];
      else if (col < 384) v = 0.f;
      else v = W_hh[(size_t)(col - 128) * 128 + k2];
    }
    Bt512[idx] = f2bf(v);
    return;
  }
  idx -= 512 * 256;

  if (idx < out_size + 64) {
    if (idx < out_size) d_out_f[idx] = 0.f;
    else cnt[idx - out_size] = 0.f;
    return;
  }
  idx -= out_size + 64;

  if (idx < NLAY * 2048) {
    int l = idx / 2048, rem = idx - l * 2048;
    int k = rem >> 4, j16 = rem & 15;
    int hh = j16 & 7;
    const float* a = ((j16 < 8) ? att_src : att_dst) + (size_t)l * 1024 + hh * 128;
    const float* w = gat_W + (size_t)l * 131072 + (size_t)k * 1024 + hh * 128;
    float s = 0.f;
    for (int cc = 0; cc < 128; ++cc) s += w[cc] * a[cc];
    waSD[(size_t)l * 2048 + rem] = s;
  }
}

// ---------------------------------------------------------------------------
// Unified GAT-chain matmul v6: C[M,128] = act(A @ B + bias).
//   A: bf16 K-TILED aggT (Ab) reg-staged 2-deep prefetch pipeline
//      (load t+2 -> compute t -> write t+1 -> barrier; each block-step
//      reads one contiguous 16KB chunk), or
//      fp32[M,K] row-major (Af) reg-staged with conversion (encoder).
//   B in FRAGMENT order -> each wave B-load is one coalesced 1KB read.
//   BM=128 rows/block, 512 threads (8 waves: 4 m-slices x 2 n-slices).
//   LDS A-tiles XOR-swizzled (chunk ^= row&7) on BOTH write and read.
//   Optional fused alpha epilogue via Cs staged in the (reused) A LDS.
// ---------------------------------------------------------------------------
__global__ __launch_bounds__(512) void mm_gat(
    const unsigned short* __restrict__ Ab, const float* __restrict__ Af,
    const short* __restrict__ Bt, const float* __restrict__ bias,
    unsigned short* __restrict__ Cb2,
    const float* __restrict__ waSD, float* __restrict__ aS,
    float* __restrict__ aD, int M, int K, int relu)
{
  __shared__ short uni[128 * 132];   // 2 A-buffers (2x8192 shorts) / Cs (stride 132)
  __shared__ float s_wa[2048];
  short* bufA = uni;
  short* bufB = uni + 128 * 64;

  const int tid = threadIdx.x;
  const int m0 = blockIdx.x * 128;
  const int wid = tid >> 6, lane = tid & 63;
  const int l15 = lane & 15, quad = lane >> 4;
  const int wm = wid & 3, wn = wid >> 2;
  const int mb = wm * 32;
  const int nb = wn * 64;

  if (waSD) {
    for (int i = tid; i < 2048; i += 512) s_wa[i] = waSD[i];
  }

  floatx4 acc[2][4];
#pragma unroll
  for (int a = 0; a < 2; ++a)
#pragma unroll
    for (int g = 0; g < 4; ++g) acc[a][g] = (floatx4){0.f, 0.f, 0.f, 0.f};

  const int nt = K >> 6;

  // thread -> (row, chunk) mapping for staging: two slots per thread
  const int r0 = tid >> 3,        j0 = tid & 7;           // rows 0..63
  const int r1 = 64 + (tid >> 3), j1 = tid & 7;           // rows 64..127

  // K-tiled A: tile base for this block (131072 shorts per 128-row tile)
  const unsigned short* AbT = Ab ? (Ab + (size_t)blockIdx.x * 131072) : nullptr;

  auto loadAbTo = [&](int kb, short8& q0, short8& q1) {
    // contiguous 16KB chunk: tileT[kb64][rr][ko]
    const unsigned short* src = AbT + (size_t)(kb >> 6) * 8192;
    q0 = *(const short8*)&src[r0 * 64 + (j0 << 3)];
    q1 = *(const short8*)&src[r1 * 64 + (j1 << 3)];
  };
  auto writeAbFrom = [&](short* buf, short8 q0, short8 q1) {
    *(short8*)&buf[r0 * 64 + ((j0 ^ (r0 & 7)) << 3)] = q0;
    *(short8*)&buf[r1 * 64 + ((j1 ^ (r1 & 7)) << 3)] = q1;
  };
  auto stageAf = [&](short* buf, int kb) {
#pragma unroll
    for (int c = 0; c < 2; ++c) {
      int id = c * 512 + tid;
      int r = id >> 3, j = id & 7;
      int row = m0 + r; if (row >= M) row = M - 1;
      const float4* m4 = (const float4*)(Af + (size_t)row * K + kb + (j << 3));
      float4 a = m4[0], b = m4[1];
      short8 p;
      p[0] = f2bf(a.x); p[1] = f2bf(a.y); p[2] = f2bf(a.z); p[3] = f2bf(a.w);
      p[4] = f2bf(b.x); p[5] = f2bf(b.y); p[6] = f2bf(b.z); p[7] = f2bf(b.w);
      *(short8*)&buf[r * 64 + ((j ^ (r & 7)) << 3)] = p;
    }
  };
  auto compute = [&](const short* buf, int kb) {
    const int rr0 = mb + l15, rr1 = mb + 16 + l15;
    const int rx = rr0 & 7;    // == rr1 & 7
    const int kb64 = kb >> 6;
#pragma unroll
    for (int kk = 0; kk < 2; ++kk) {
      int c = kk * 4 + quad;
      int cs = (c ^ rx) << 3;
      short8 a0 = *(const short8*)&buf[rr0 * 64 + cs];
      short8 a1 = *(const short8*)&buf[rr1 * 64 + cs];
#pragma unroll
      for (int g = 0; g < 4; ++g) {
        int col16 = (nb >> 4) + g;
        int frag = (col16 * nt + kb64) * 2 + kk;
        short8 b = *(const short8*)&Bt[(size_t)frag * 512 + lane * 8];
        acc[0][g] = __builtin_amdgcn_mfma_f32_16x16x32_bf16(a0, b, acc[0][g], 0, 0, 0);
        acc[1][g] = __builtin_amdgcn_mfma_f32_16x16x32_bf16(a1, b, acc[1][g], 0, 0, 0);
      }
    }
  };

  // ---- K loop -------------------------------------------------------------
  if (Ab) {
    // 2-deep prefetch, statically 2-unrolled (nt = 16, even):
    short8 pA0, pA1, pB0, pB1;
    loadAbTo(0, pA0, pA1);
    writeAbFrom(bufA, pA0, pA1);
    loadAbTo(64, pB0, pB1);
    __syncthreads();
    for (int t = 0; t < nt; t += 2) {
      if (t + 2 < nt) loadAbTo((t + 2) << 6, pA0, pA1);
      compute(bufA, t << 6);
      if (t + 1 < nt) writeAbFrom(bufB, pB0, pB1);
      __syncthreads();
      if (t + 3 < nt) loadAbTo((t + 3) << 6, pB0, pB1);
      if (t + 1 < nt) compute(bufB, (t + 1) << 6);
      if (t + 2 < nt) writeAbFrom(bufA, pA0, pA1);
      __syncthreads();
    }
  } else {
    for (int t = 0; t < nt; ++t) {
      if (t) __syncthreads();
      stageAf(bufA, t << 6);
      __syncthreads();
      compute(bufA, t << 6);
    }
    __syncthreads();
  }

  // ---- epilogue: bias + act, write C (global) and Cs (LDS, for alphas) ----
#pragma unroll
  for (int mt = 0; mt < 2; ++mt) {
#pragma unroll
    for (int g = 0; g < 4; ++g) {
      int colg = nb + g * 16 + l15;
      float bv = bias ? bias[colg] : 0.f;
#pragma unroll
      for (int r = 0; r < 4; ++r) {
        int rl = mb + mt * 16 + quad * 4 + r;
        int rowg = m0 + rl;
        float v = acc[mt][g][r] + bv;
        if (relu) v = fmaxf(v, 0.f);
        unsigned short bv16 = (unsigned short)f2bf(v);
        if (waSD) uni[rl * 132 + colg] = (short)bv16;
        if (rowg < M) Cb2[(size_t)rowg * HIDC + colg] = bv16;
      }
    }
  }

  if (waSD) {
    __syncthreads();
    int r = tid >> 2, jq = tid & 3;
    int row = m0 + r;
    float s0 = 0.f, s1 = 0.f, s2 = 0.f, s3 = 0.f;
    const unsigned* c32 = (const unsigned*)uni;   // stride 66 uints per row
#pragma unroll 8
    for (int c2 = 0; c2 < 64; ++c2) {
      unsigned u = c32[r * 66 + c2];
      float hx = __uint_as_float(u << 16);
      float hy = __uint_as_float(u & 0xffff0000u);
      const float* w0 = &s_wa[(c2 * 2) * 16 + jq * 4];
      s0 = fmaf(hx, w0[0], fmaf(hy, w0[16], s0));
      s1 = fmaf(hx, w0[1], fmaf(hy, w0[17], s1));
      s2 = fmaf(hx, w0[2], fmaf(hy, w0[18], s2));
      s3 = fmaf(hx, w0[3], fmaf(hy, w0[19], s3));
    }
    if (row < M) {
      float4 v4 = make_float4(s0, s1, s2, s3);
      if (jq < 2) ((float4*)aS)[(size_t)row * 2 + jq] = v4;
      else        ((float4*)aD)[(size_t)row * 2 + (jq - 2)] = v4;
    }
  }
}

// ---------------------------------------------------------------------------
// Fused GRU (v1 structure + fragment-order B): per block, 64 rows x ALL 512
// S-cols of [hb|mem]@Bt512^T (K=256, reg-staged LDS double buffer), then
// gates + GRU blend + mean-pool accumulation entirely in-register.
// ---------------------------------------------------------------------------
__global__ __launch_bounds__(512) void gru_fused(
    const unsigned short* __restrict__ hb, const float* __restrict__ mem,
    const short* __restrict__ Bt512,
    const float* __restrict__ bI, const float* __restrict__ bH,
    const int* __restrict__ batch, float* __restrict__ pooled,
    float* __restrict__ cnt, int N)
{
  __shared__ short As[2 * 64 * 64];   // double buffer, 16 KB
  short* bufA = As;
  short* bufB = As + 64 * 64;

  const int tid = threadIdx.x;
  const int m0 = blockIdx.x * 64;
  const int wid = tid >> 6, lane = tid & 63;
  const int l15 = lane & 15, quad = lane >> 4;
  const int wm = wid & 1, wn = wid >> 1;     // 2 m-slices x 4 n-slices
  const int mb = wm * 32;

  floatx4 acc[2][8];
#pragma unroll
  for (int a = 0; a < 2; ++a)
#pragma unroll
    for (int g = 0; g < 8; ++g) acc[a][g] = (floatx4){0.f, 0.f, 0.f, 0.f};

  // staging: 64 rows x 64 k-shorts = 4096 shorts; 1 slot of 16B per thread
  const int r0 = tid >> 3, j0 = tid & 7;
  short8 pr;
  auto loadA = [&](int kb) {
    int row = m0 + r0; if (row >= N) row = N - 1;
    if (kb < 128) {
      pr = *(const short8*)&hb[(size_t)row * 128 + kb + (j0 << 3)];
    } else {
      const float4* m4 = (const float4*)(mem + (size_t)row * 128 + (kb - 128) + (j0 << 3));
      float4 a = m4[0], b = m4[1];
      short8 p;
      p[0] = f2bf(a.x); p[1] = f2bf(a.y); p[2] = f2bf(a.z); p[3] = f2bf(a.w);
      p[4] = f2bf(b.x); p[5] = f2bf(b.y); p[6] = f2bf(b.z); p[7] = f2bf(b.w);
      pr = p;
    }
  };
  auto writeA = [&](short* buf) {
    *(short8*)&buf[r0 * 64 + ((j0 ^ (r0 & 7)) << 3)] = pr;
  };
  auto compute = [&](const short* buf, int kb) {
    const int rr0 = mb + l15, rr1 = mb + 16 + l15;
    const int rx = rr0 & 7;
    const int kb64 = kb >> 6;
#pragma unroll
    for (int kk = 0; kk < 2; ++kk) {
      int c = kk * 4 + quad;
      int cs = (c ^ rx) << 3;
      short8 a0 = *(const short8*)&buf[rr0 * 64 + cs];
      short8 a1 = *(const short8*)&buf[rr1 * 64 + cs];
#pragma unroll
      for (int g = 0; g < 8; ++g) {
        // gate (g>>1), output col16 = (g>>1)*8 + wn*2 + (g&1)
        int col16 = ((g >> 1) << 3) + (wn << 1) + (g & 1);
        int frag = (col16 * 4 + kb64) * 2 + kk;
        short8 b = *(const short8*)&Bt512[(size_t)frag * 512 + lane * 8];
        acc[0][g] = __builtin_amdgcn_mfma_f32_16x16x32_bf16(a0, b, acc[0][g], 0, 0, 0);
        acc[1][g] = __builtin_amdgcn_mfma_f32_16x16x32_bf16(a1, b, acc[1][g], 0, 0, 0);
      }
    }
  };

  // K loop: 4 steps, double-buffered
  loadA(0);
  writeA(bufA);
  __syncthreads();
  for (int t = 0; t < 4; ++t) {
    short* cur = (t & 1) ? bufB : bufA;
    short* nxt = (t & 1) ? bufA : bufB;
    if (t < 3) loadA((t + 1) << 6);
    compute(cur, t << 6);
    if (t < 3) writeA(nxt);
    __syncthreads();
  }

  // ---- epilogue: gates + blend + pooling ----------------------------------
  int nlast = (m0 + 63 < N) ? (m0 + 63) : (N - 1);
  const bool unif = (batch[m0] == batch[nlast]);
  const int bg = batch[m0];

#pragma unroll
  for (int sub = 0; sub < 2; ++sub) {
    const int c = wn * 32 + sub * 16 + l15;
    const float bI0 = bI[c],       bH0 = bH[c];
    const float bI1 = bI[128 + c], bH1 = bH[128 + c];
    const float bI2 = bI[256 + c], bH2 = bH[256 + c];
    float pv = 0.f;
#pragma unroll
    for (int mt = 0; mt < 2; ++mt) {
#pragma unroll
      for (int r = 0; r < 4; ++r) {
        int row = m0 + mb + mt * 16 + quad * 4 + r;
        bool v = (row < N);
        int rowc = v ? row : (N - 1);
        float sr  = acc[mt][0 + sub][r] + bI0 + bH0;
        float sz  = acc[mt][2 + sub][r] + bI1 + bH1;
        float gin = acc[mt][4 + sub][r] + bI2;
        float ghn = acc[mt][6 + sub][r] + bH2;
        float rg = 1.f / (1.f + __expf(-sr));
        float zg = 1.f / (1.f + __expf(-sz));
        float ncv = tanhf(gin + rg * ghn);
        float val = (1.f - zg) * ncv + zg * mem[(size_t)rowc * 128 + c];
        if (!v) val = 0.f;
        if (unif) {
          pv += val;
        } else if (v) {
          atomicAdd(&pooled[(size_t)batch[row] * 128 + c], val);
          if (wn == 0 && l15 == 0 && sub == 0)
            atomicAdd(&cnt[batch[row]], 1.f);
        }
      }
    }
    if (unif) {
      pv += __shfl_xor(pv, 16);
      pv += __shfl_xor(pv, 32);
      if (quad == 0) atomicAdd(&pooled[(size_t)bg * 128 + c], pv);
    }
  }
  if (unif && tid == 0) atomicAdd(&cnt[bg], (float)(nlast - m0 + 1));
}

// ---------------------------------------------------------------------------
// CSR build
// ---------------------------------------------------------------------------
__global__ void hist_kernel(const int* __restrict__ ei, int* __restrict__ deg, int E, int N)
{
  int i = blockIdx.x * 256 + threadIdx.x;
  if (i >= E + N) return;
  int dst = (i < E) ? ei[E + i] : (i - E);
  atomicAdd(&deg[dst], 1);
}

__global__ __launch_bounds__(1024) void scan1_kernel(
    const int* __restrict__ deg, int* __restrict__ rowptr,
    int* __restrict__ bsum, int N)
{
  __shared__ int sd[1024];
  int i = blockIdx.x * 1024 + threadIdx.x;
  int v = (i < N) ? deg[i] : 0;
  sd[threadIdx.x] = v;
  __syncthreads();
  for (int off = 1; off < 1024; off <<= 1) {
    int t = (threadIdx.x >= off) ? sd[threadIdx.x - off] : 0;
    __syncthreads();
    sd[threadIdx.x] += t;
    __syncthreads();
  }
  if (i < N) rowptr[i] = sd[threadIdx.x] - v;
  if (threadIdx.x == 1023) bsum[blockIdx.x] = sd[1023];
}

__global__ __launch_bounds__(64) void scan2_kernel(int* __restrict__ bsum, int nb)
{
  int lane = threadIdx.x;
  int v = (lane < nb) ? bsum[lane] : 0;
  int incl = v;
  for (int off = 1; off < 64; off <<= 1) {
    int t = __shfl_up(incl, off);
    if (lane >= off) incl += t;
  }
  if (lane < nb) bsum[lane] = incl - v;
}

__global__ void scatter_kernel(const int* __restrict__ ei, const int* __restrict__ rowptr,
                               const int* __restrict__ bsum, int* __restrict__ cursor,
                               int* __restrict__ csr_src, int E, int N)
{
  int i = blockIdx.x * 256 + threadIdx.x;
  if (i >= E + N) return;
  int src, dst;
  if (i < E) { src = ei[i]; dst = ei[E + i]; }
  else { src = i - E; dst = i - E; }
  int pos = rowptr[dst] + bsum[dst >> 10] + atomicAdd(&cursor[dst], 1);
  csr_src[pos] = src;
}

// ---------------------------------------------------------------------------
// GAT aggregation v7: one wave per dst; output written K-TILED for mm_gat:
//   aggT[rb][kb64][rr][ko] with rb=dst>>7, rr=dst&127, k=q*128+lane*2.
// ---------------------------------------------------------------------------
#define PKX(acc, p) asm("v_pk_fma_f32 %0, %2, %1, %0 op_sel:[0,0,0] op_sel_hi:[1,0,1]" \
                        : "+v"(acc) : "v"(hxy), "v"(p))
#define PKY(acc, p) asm("v_pk_fma_f32 %0, %2, %1, %0 op_sel:[0,1,0] op_sel_hi:[1,1,1]" \
                        : "+v"(acc) : "v"(hxy), "v"(p))

__global__ __launch_bounds__(256, 8) void gat_agg6(
    const unsigned short* __restrict__ hb, const int* __restrict__ rowptr,
    const int* __restrict__ bsum, const int* __restrict__ csr_src,
    const float* __restrict__ aS, const float* __restrict__ aD,
    unsigned short* __restrict__ agg, int N, int EN)
{
  __shared__ float s_p[4][48][8];
  __shared__ int   s_src[4][48];
  const int wid = threadIdx.x >> 6;
  const int lane = threadIdx.x & 63;
  const int dst = blockIdx.x * 4 + wid;
  if (dst >= N) return;
  const int el = lane >> 3, hh = lane & 7;
  const int start = rowptr[dst] + bsum[dst >> 10];
  const int endp = (dst + 1 < N) ? (rowptr[dst + 1] + bsum[(dst + 1) >> 10]) : EN;
  const int deg = endp - start;
  const float adh = aD[(size_t)dst * 8 + hh];
  const int ng = (deg < MAXI * 8) ? ((deg + 7) >> 3) : MAXI;

  float m = -1e30f;
  for (int i = 0; i < ng; ++i) {
    int e = i * 8 + el;
    int s = 0; float v = -1e30f;
    if (e < deg) {
      s = csr_src[start + e];
      v = aS[(size_t)s * 8 + hh] + adh;
      v = (v > 0.f) ? v : 0.2f * v;
    }
    if (hh == 0) s_src[wid][e] = s;
    s_p[wid][e][hh] = v;
    m = fmaxf(m, v);
  }
  for (int e0 = MAXI * 8; e0 < deg; e0 += 8) {
    int e = e0 + el;
    if (e < deg) {
      int s = csr_src[start + e];
      float v = aS[(size_t)s * 8 + hh] + adh;
      v = (v > 0.f) ? v : 0.2f * v;
      m = fmaxf(m, v);
    }
  }

  const unsigned* hb32 = (const unsigned*)hb;
  unsigned hv[8];
  {
    int4 sa = *(const int4*)&s_src[wid][0];
    int4 sb = *(const int4*)&s_src[wid][4];
    hv[0] = hb32[(unsigned)sa.x * 64 + lane];
    hv[1] = hb32[(unsigned)sa.y * 64 + lane];
    hv[2] = hb32[(unsigned)sa.z * 64 + lane];
    hv[3] = hb32[(unsigned)sa.w * 64 + lane];
    hv[4] = hb32[(unsigned)sb.x * 64 + lane];
    hv[5] = hb32[(unsigned)sb.y * 64 + lane];
    hv[6] = hb32[(unsigned)sb.z * 64 + lane];
    hv[7] = hb32[(unsigned)sb.w * 64 + lane];
  }

  m = fmaxf(m, __shfl_xor(m, 8));
  m = fmaxf(m, __shfl_xor(m, 16));
  m = fmaxf(m, __shfl_xor(m, 32));

  float dsum = 0.f;
  for (int i = 0; i < ng; ++i) {
    int e = i * 8 + el;
    float v = s_p[wid][e][hh];
    float p = (v > -1e29f) ? __expf(v - m) : 0.f;
    dsum += p;
    s_p[wid][e][hh] = p;
  }

  floatx2 axp[4], ayp[4];
#pragma unroll
  for (int j = 0; j < 4; ++j) {
    axp[j] = (floatx2){0.f, 0.f};
    ayp[j] = (floatx2){0.f, 0.f};
  }

  for (int i = 0; i < ng; ++i) {
    unsigned hn[8];
    if (i + 1 < ng) {
      int4 sa = *(const int4*)&s_src[wid][(i + 1) * 8];
      int4 sb = *(const int4*)&s_src[wid][(i + 1) * 8 + 4];
      hn[0] = hb32[(unsigned)sa.x * 64 + lane];
      hn[1] = hb32[(unsigned)sa.y * 64 + lane];
      hn[2] = hb32[(unsigned)sa.z * 64 + lane];
      hn[3] = hb32[(unsigned)sa.w * 64 + lane];
      hn[4] = hb32[(unsigned)sb.x * 64 + lane];
      hn[5] = hb32[(unsigned)sb.y * 64 + lane];
      hn[6] = hb32[(unsigned)sb.z * 64 + lane];
      hn[7] = hb32[(unsigned)sb.w * 64 + lane];
    }
#pragma unroll
    for (int ee = 0; ee < 8; ++ee) {
      unsigned u = hv[ee];
      floatx2 hxy;
      hxy[0] = __uint_as_float(u << 16);
      hxy[1] = __uint_as_float(u & 0xffff0000u);
      floatx4 pA = *(const floatx4*)&s_p[wid][i * 8 + ee][0];
      floatx4 pB = *(const floatx4*)&s_p[wid][i * 8 + ee][4];
      floatx2 p0 = pA.lo, p1 = pA.hi, p2 = pB.lo, p3 = pB.hi;
      PKX(axp[0], p0); PKY(ayp[0], p0);
      PKX(axp[1], p1); PKY(ayp[1], p1);
      PKX(axp[2], p2); PKY(ayp[2], p2);
      PKX(axp[3], p3); PKY(ayp[3], p3);
    }
    if (i + 1 < ng) {
#pragma unroll
      for (int q = 0; q < 8; ++q) hv[q] = hn[q];
    }
  }

  const int c2 = lane * 2;
  for (int e0 = MAXI * 8; e0 < deg; e0 += 8) {
    int e = e0 + el;
    float p = 0.f; int s = 0;
    if (e < deg) {
      s = csr_src[start + e];
      float v = aS[(size_t)s * 8 + hh] + adh;
      v = (v > 0.f) ? v : 0.2f * v;
      p = __expf(v - m);
    }
    dsum += p;
    int cnt = deg - e0; if (cnt > 8) cnt = 8;
    for (int ee = 0; ee < cnt; ++ee) {
      int se = __shfl(s, ee * 8);
      unsigned u = *(const unsigned*)&hb[(size_t)se * 128 + c2];
      float hx = __uint_as_float(u << 16);
      float hy = __uint_as_float(u & 0xffff0000u);
#pragma unroll
      for (int q = 0; q < 8; ++q) {
        float pq = __shfl(p, ee * 8 + q);
        axp[q >> 1][q & 1] = fmaf(pq, hx, axp[q >> 1][q & 1]);
        ayp[q >> 1][q & 1] = fmaf(pq, hy, ayp[q >> 1][q & 1]);
      }
    }
  }

  dsum += __shfl_xor(dsum, 8);
  dsum += __shfl_xor(dsum, 16);
  dsum += __shfl_xor(dsum, 32);
  float inv = 1.f / (dsum + 1e-16f);

  // K-tiled write: k = q*128 + lane*2 -> kb64 = q*2 + (lane>>5), ko = (lane&31)*2
  const int rb = dst >> 7, rr = dst & 127;
  const size_t tbase = (size_t)rb * 131072 + (size_t)rr * 64;
#pragma unroll
  for (int q = 0; q < 8; ++q) {
    float invq = __shfl(inv, q);
    float ax = axp[q >> 1][q & 1] * invq;
    float ay = ayp[q >> 1][q & 1] * invq;
    unsigned pk = ((unsigned)(unsigned short)f2bf(ay) << 16) |
                  (unsigned)(unsigned short)f2bf(ax);
    int kb64 = q * 2 + (lane >> 5);
    *(unsigned*)&agg[tbase + (size_t)kb64 * 8192 + (lane & 31) * 2] = pk;
  }
}

// ---------------------------------------------------------------------------
// finalize pooled, classifier MLP, softmax
// ---------------------------------------------------------------------------
__global__ __launch_bounds__(64) void classifier_kernel(
    float* __restrict__ pooled, const float* __restrict__ cnt,
    const float* __restrict__ c1W, const float* __restrict__ c1b,
    const float* __restrict__ c2W, const float* __restrict__ c2b,
    float* __restrict__ logits, float* __restrict__ preds)
{
  int g = blockIdx.x, j = threadIdx.x;
  __shared__ float sp[128];
  __shared__ float hid[64];
  __shared__ float lg[3];
  float invc = 1.f / fmaxf(cnt[g], 1.f);
  float p0 = pooled[(size_t)g * 128 + j] * invc;
  float p1 = pooled[(size_t)g * 128 + 64 + j] * invc;
  pooled[(size_t)g * 128 + j] = p0;
  pooled[(size_t)g * 128 + 64 + j] = p1;
  sp[j] = p0; sp[j + 64] = p1;
  __syncthreads();
  float a = c1b[j];
#pragma unroll
  for (int k = 0; k < 128; ++k) a = fmaf(sp[k], c1W[k * 64 + j], a);
  hid[j] = fmaxf(a, 0.f);
  __syncthreads();
  if (j < NCLS) {
    float t = c2b[j];
#pragma unroll
    for (int k = 0; k < 64; ++k) t = fmaf(hid[k], c2W[k * NCLS + j], t);
    logits[(size_t)g * NCLS + j] = t;
    lg[j] = t;
  }
  __syncthreads();
  if (j < NCLS) {
    float mx = fmaxf(lg[0], fmaxf(lg[1], lg[2]));
    float e0 = __expf(lg[0] - mx), e1 = __expf(lg[1] - mx), e2 = __expf(lg[2] - mx);
    float mine = (j == 0) ? e0 : ((j == 1) ? e1 : e2);
    preds[(size_t)g * NCLS + j] = mine / (e0 + e1 + e2);
  }
}

// ---------------------------------------------------------------------------
extern "C" void kernel_launch(void* const* d_in, const int* in_sizes, int n_in,
                              void* d_out, int out_size, void* d_ws, size_t ws_size,
                              hipStream_t stream)
{
  const float* x       = (const float*)d_in[0];
  const int*   ei      = (const int*)d_in[1];
  const int*   batch   = (const int*)d_in[2];
  const float* memory  = (const float*)d_in[3];
  const float* enc_W   = (const float*)d_in[4];
  const float* enc_b   = (const float*)d_in[5];
  const float* gat_W   = (const float*)d_in[6];   // [NL,128,1024]
  const float* att_src = (const float*)d_in[7];
  const float* att_dst = (const float*)d_in[8];
  const float* gat_b   = (const float*)d_in[9];
  const float* W_ih    = (const float*)d_in[10];
  const float* W_hh    = (const float*)d_in[11];
  const float* b_ih    = (const float*)d_in[12];
  const float* b_hh    = (const float*)d_in[13];
  const float* c1W     = (const float*)d_in[14];
  const float* c1b     = (const float*)d_in[15];
  const float* c2W     = (const float*)d_in[16];
  const float* c2b     = (const float*)d_in[17];

  const int N = in_sizes[0] / HIDC;
  const int E = in_sizes[1] / 2;
  const int EN = E + N;
  const int NB = (N + 1023) / 1024;
  const int MB = (N + 127) / 128;

  char* ws = (char*)d_ws;
  size_t off = 0;
  auto alloc = [&](size_t bytes) -> void* {
    void* p = ws + off;
    off += (bytes + 255) & ~(size_t)255;
    return p;
  };
  unsigned short* hb0 = (unsigned short*)alloc((size_t)N * HIDC * 2);
  unsigned short* hb1 = (unsigned short*)alloc((size_t)N * HIDC * 2);
  unsigned short* agg = (unsigned short*)alloc((size_t)MB * 131072 * 2);  // K-tiled
  float* aS     = (float*)alloc((size_t)N * NHEAD * 4);
  float* aD     = (float*)alloc((size_t)N * NHEAD * 4);
  short* encT   = (short*)alloc((size_t)128 * 128 * 2);
  short* Wp     = (short*)alloc((size_t)NLAY * 131072 * 2);
  float* waSD   = (float*)alloc((size_t)NLAY * 2048 * 4);
  short* Bt512  = (short*)alloc((size_t)512 * 256 * 2);
  int*   rowptr = (int*)alloc((size_t)(N + 1) * 4);
  size_t zoff0 = off;
  int*   cursor = (int*)alloc((size_t)N * 4);
  int*   degtmp = (int*)alloc((size_t)N * 4);
  size_t zbytes = off - zoff0;
  int*   bsum   = (int*)alloc(64 * 4);
  int*   csr    = (int*)alloc((size_t)EN * 4);
  float* cntbuf = (float*)alloc(64 * 4);

  float* out_logits = (float*)d_out;
  float* out_pooled = (float*)d_out + NGRAPH * NCLS;
  float* out_preds  = (float*)d_out + NGRAPH * NCLS + NGRAPH * HIDC;

  hipMemsetAsync(cursor, 0, zbytes, stream);

  // fused prep: weights (fragment-order B) + d_out/cnt zeroing (one dispatch)
  {
    int total = 16384 + NLAY * 131072 + 512 * 256 + (out_size + 64) + NLAY * 2048;
    prep_kernel<<<(total + 255) / 256, 256, 0, stream>>>(
        enc_W, encT, gat_W, Wp, W_ih, W_hh, Bt512, att_src, att_dst, waSD,
        (float*)d_out, out_size, cntbuf);
  }

  // CSR build
  hist_kernel<<<(EN + 255) / 256, 256, 0, stream>>>(ei, degtmp, E, N);
  scan1_kernel<<<NB, 1024, 0, stream>>>(degtmp, rowptr, bsum, N);
  scan2_kernel<<<1, 64, 0, stream>>>(bsum, NB);
  scatter_kernel<<<(EN + 255) / 256, 256, 0, stream>>>(ei, rowptr, bsum, cursor,
                                                       csr, E, N);

  // encoder: hb0 = bf16(relu(x @ enc_W + enc_b)) + fused alphas for layer 0
  mm_gat<<<MB, 512, 0, stream>>>(nullptr, x, encT, enc_b, hb0,
                                 waSD, aS, aD, N, 128, 1);

  unsigned short* hbcur = hb0;
  unsigned short* hbnxt = hb1;
  for (int l = 0; l < NLAY; ++l) {
    gat_agg6<<<(N + 3) / 4, 256, 0, stream>>>(hbcur, rowptr, bsum, csr, aS, aD,
                                              agg, N, EN);
    const float* wnext = (l < NLAY - 1) ? (waSD + (size_t)(l + 1) * 2048) : nullptr;
    mm_gat<<<MB, 512, 0, stream>>>(agg, nullptr, Wp + (size_t)l * 131072,
                                   gat_b + (size_t)l * HIDC, hbnxt,
                                   wnext, aS, aD, N, 1024, (l < NLAY - 1) ? 1 : 0);
    unsigned short* tb = hbcur; hbcur = hbnxt; hbnxt = tb;
  }

  // fused GRU: matmul + gates + blend + mean-pool in one dispatch
  gru_fused<<<(N + 63) / 64, 512, 0, stream>>>(hbcur, memory, Bt512, b_ih, b_hh,
                                               batch, out_pooled, cntbuf, N);

  // classifier
  classifier_kernel<<<NGRAPH, 64, 0, stream>>>(out_pooled, cntbuf, c1W, c1b, c2W, c2b,
                                               out_logits, out_preds);
}

// Round 15
// 648.180 us; speedup vs baseline: 1.0810x; 1.0810x over previous
//
#include <hip/hip_runtime.h>
#include <cstdint>
#include <cstddef>

#define HIDC 128
#define NHEAD 8
#define NLAY 3
#define NGRAPH 64
#define NCLS 3
#define MAXI 6   // fast path deg <= 48

typedef __attribute__((ext_vector_type(8))) short short8;
typedef __attribute__((ext_vector_type(4))) float floatx4;
typedef __attribute__((ext_vector_type(2))) float floatx2;

__device__ inline short f2bf(float x) {
  unsigned u = __float_as_uint(x);
  unsigned r = (u + 0x7fff + ((u >> 16) & 1)) >> 16;   // RNE
  return (short)r;
}
__device__ inline float bf2f(unsigned short u) {
  return __uint_as_float(((unsigned)u) << 16);
}

// ---------------------------------------------------------------------------
// B matrices are stored in MFMA-FRAGMENT order:
//   Bf[frag*512 + lane*8 + j]  ==  B[col16*16 + (lane&15)][kb64*64 + kk*32 + (lane>>4)*8 + j]
//   frag = (col16 * (K/64) + kb64) * 2 + kk
// so each wave's B operand is ONE contiguous 1KB coalesced load.
// ---------------------------------------------------------------------------

// ---------------------------------------------------------------------------
// Unified prep kernel: encT/Wp/Bt512 built in fragment order, waSD dots,
// d_out + cnt zeroing.
// ---------------------------------------------------------------------------
__global__ __launch_bounds__(256) void prep_kernel(
    const float* __restrict__ enc_W, short* __restrict__ encT,
    const float* __restrict__ gat_W, short* __restrict__ Wp,
    const float* __restrict__ W_ih, const float* __restrict__ W_hh,
    short* __restrict__ Bt512,
    const float* __restrict__ att_src, const float* __restrict__ att_dst,
    float* __restrict__ waSD,
    float* __restrict__ d_out_f, int out_size, float* __restrict__ cnt)
{
  int idx = blockIdx.x * 256 + threadIdx.x;

  // encT: K=128, 8 col16 x 2 kb64 x 2 kk = 32 frags x 512 shorts
  if (idx < 16384) {
    int frag = idx >> 9, rem = idx & 511;
    int lane = rem >> 3, j = rem & 7;
    int col16 = frag >> 2, kb64 = (frag >> 1) & 1, kk = frag & 1;
    int col = col16 * 16 + (lane & 15);
    int k = kb64 * 64 + kk * 32 + ((lane >> 4) << 3) + j;
    encT[idx] = f2bf(enc_W[(size_t)k * 128 + col]);
    return;
  }
  idx -= 16384;

  // Wp: per layer K=1024, 8 col16 x 16 kb64 x 2 kk = 256 frags x 512 shorts
  if (idx < NLAY * 131072) {
    int l = idx >> 17, rem17 = idx & 131071;
    int frag = rem17 >> 9, rem = rem17 & 511;
    int lane = rem >> 3, j = rem & 7;
    int col16 = frag >> 5, kb64 = (frag >> 1) & 15, kk = frag & 1;
    int cc = col16 * 16 + (lane & 15);
    int k1024 = kb64 * 64 + kk * 32 + ((lane >> 4) << 3) + j;
    int hh = k1024 >> 7, k = k1024 & 127;
    Wp[idx] = f2bf(gat_W[(size_t)l * 131072 + (size_t)k * 1024 + hh * 128 + cc]
                   * 0.125f);
    return;
  }
  idx -= NLAY * 131072;

  // Bt512: K=256, 32 col16 x 4 kb64 x 2 kk = 256 frags x 512 shorts
  if (idx < 512 * 256) {
    int frag = idx >> 9, rem = idx & 511;
    int lane = rem >> 3, j = rem & 7;
    int col16 = frag >> 3, kb64 = (frag >> 1) & 3, kk = frag & 1;
    int col = col16 * 16 + (lane & 15);
    int k = kb64 * 64 + kk * 32 + ((lane >> 4) << 3) + j;
    float v;
    if (k < 128) {
      v = (col < 384) ? W_ih[(size_t)col * 128 + k] : 0.f;
    } else {
      int k2 = k - 128;
      if (col < 256) v = W_hh[(size_t)col * 128 + k2];
      else if (col < 384) v = 0.f;
      else v = W_hh[(size_t)(col - 128) * 128 + k2];
    }
    Bt512[idx] = f2bf(v);
    return;
  }
  idx -= 512 * 256;

  if (idx < out_size + 64) {
    if (idx < out_size) d_out_f[idx] = 0.f;
    else cnt[idx - out_size] = 0.f;
    return;
  }
  idx -= out_size + 64;

  if (idx < NLAY * 2048) {
    int l = idx / 2048, rem = idx - l * 2048;
    int k = rem >> 4, j16 = rem & 15;
    int hh = j16 & 7;
    const float* a = ((j16 < 8) ? att_src : att_dst) + (size_t)l * 1024 + hh * 128;
    const float* w = gat_W + (size_t)l * 131072 + (size_t)k * 1024 + hh * 128;
    float s = 0.f;
    for (int cc = 0; cc < 128; ++cc) s += w[cc] * a[cc];
    waSD[(size_t)l * 2048 + rem] = s;
  }
}

// ---------------------------------------------------------------------------
// Unified GAT-chain matmul v5: C[M,128] = act(A @ B + bias).
//   A: bf16[M,K] (Ab) reg-staged 2-DEEP prefetch pipeline (load t+2 ->
//      compute t -> write t+1 -> barrier; extra tile lives in registers;
//      K=1024 so nt=16 even, statically 2-unrolled), or
//      fp32[M,K] (Af) reg-staged with conversion (unpipelined, small K).
//   B in FRAGMENT order -> each wave B-load is one coalesced 1KB read.
//   BM=128 rows/block, 512 threads (8 waves: 4 m-slices x 2 n-slices).
//   LDS A-tiles XOR-swizzled (chunk ^= row&7) on BOTH write and read.
//   Optional fused alpha epilogue via Cs staged in the (reused) A LDS.
// ---------------------------------------------------------------------------
__global__ __launch_bounds__(512) void mm_gat(
    const unsigned short* __restrict__ Ab, const float* __restrict__ Af,
    const short* __restrict__ Bt, const float* __restrict__ bias,
    unsigned short* __restrict__ Cb2,
    const float* __restrict__ waSD, float* __restrict__ aS,
    float* __restrict__ aD, int M, int K, int relu)
{
  __shared__ short uni[128 * 132];   // 2 A-buffers (2x8192 shorts) / Cs (stride 132)
  __shared__ float s_wa[2048];
  short* bufA = uni;
  short* bufB = uni + 128 * 64;

  const int tid = threadIdx.x;
  const int m0 = blockIdx.x * 128;
  const int wid = tid >> 6, lane = tid & 63;
  const int l15 = lane & 15, quad = lane >> 4;
  const int wm = wid & 3, wn = wid >> 2;
  const int mb = wm * 32;
  const int nb = wn * 64;

  if (waSD) {
    for (int i = tid; i < 2048; i += 512) s_wa[i] = waSD[i];
  }

  floatx4 acc[2][4];
#pragma unroll
  for (int a = 0; a < 2; ++a)
#pragma unroll
    for (int g = 0; g < 4; ++g) acc[a][g] = (floatx4){0.f, 0.f, 0.f, 0.f};

  const int nt = K >> 6;

  // thread -> (row, chunk) mapping for staging: two slots per thread
  const int r0 = tid >> 3,        j0 = tid & 7;           // rows 0..63
  const int r1 = 64 + (tid >> 3), j1 = tid & 7;           // rows 64..127

  auto loadAbTo = [&](int kb, short8& q0, short8& q1) {
    int row0 = m0 + r0; if (row0 >= M) row0 = M - 1;
    int row1 = m0 + r1; if (row1 >= M) row1 = M - 1;
    q0 = *(const short8*)&Ab[(size_t)row0 * K + kb + (j0 << 3)];
    q1 = *(const short8*)&Ab[(size_t)row1 * K + kb + (j1 << 3)];
  };
  auto writeAbFrom = [&](short* buf, short8 q0, short8 q1) {
    *(short8*)&buf[r0 * 64 + ((j0 ^ (r0 & 7)) << 3)] = q0;
    *(short8*)&buf[r1 * 64 + ((j1 ^ (r1 & 7)) << 3)] = q1;
  };
  auto stageAf = [&](short* buf, int kb) {
#pragma unroll
    for (int c = 0; c < 2; ++c) {
      int id = c * 512 + tid;
      int r = id >> 3, j = id & 7;
      int row = m0 + r; if (row >= M) row = M - 1;
      const float4* m4 = (const float4*)(Af + (size_t)row * K + kb + (j << 3));
      float4 a = m4[0], b = m4[1];
      short8 p;
      p[0] = f2bf(a.x); p[1] = f2bf(a.y); p[2] = f2bf(a.z); p[3] = f2bf(a.w);
      p[4] = f2bf(b.x); p[5] = f2bf(b.y); p[6] = f2bf(b.z); p[7] = f2bf(b.w);
      *(short8*)&buf[r * 64 + ((j ^ (r & 7)) << 3)] = p;
    }
  };
  auto compute = [&](const short* buf, int kb) {
    const int rr0 = mb + l15, rr1 = mb + 16 + l15;
    const int rx = rr0 & 7;    // == rr1 & 7
    const int kb64 = kb >> 6;
#pragma unroll
    for (int kk = 0; kk < 2; ++kk) {
      int c = kk * 4 + quad;
      int cs = (c ^ rx) << 3;
      short8 a0 = *(const short8*)&buf[rr0 * 64 + cs];
      short8 a1 = *(const short8*)&buf[rr1 * 64 + cs];
#pragma unroll
      for (int g = 0; g < 4; ++g) {
        int col16 = (nb >> 4) + g;
        int frag = (col16 * nt + kb64) * 2 + kk;
        short8 b = *(const short8*)&Bt[(size_t)frag * 512 + lane * 8];
        acc[0][g] = __builtin_amdgcn_mfma_f32_16x16x32_bf16(a0, b, acc[0][g], 0, 0, 0);
        acc[1][g] = __builtin_amdgcn_mfma_f32_16x16x32_bf16(a1, b, acc[1][g], 0, 0, 0);
      }
    }
  };

  // ---- K loop -------------------------------------------------------------
  if (Ab) {
    // 2-deep prefetch, statically 2-unrolled (nt = 16, even):
    //   even step t:  load(t+2)->pA | compute(bufA=t) | write pB(t+1)->bufB
    //   odd  step:    load(t+3)->pB | compute(bufB=t+1) | write pA(t+2)->bufA
    short8 pA0, pA1, pB0, pB1;
    loadAbTo(0, pA0, pA1);
    writeAbFrom(bufA, pA0, pA1);
    loadAbTo(64, pB0, pB1);
    __syncthreads();
    for (int t = 0; t < nt; t += 2) {
      if (t + 2 < nt) loadAbTo((t + 2) << 6, pA0, pA1);
      compute(bufA, t << 6);
      if (t + 1 < nt) writeAbFrom(bufB, pB0, pB1);
      __syncthreads();
      if (t + 3 < nt) loadAbTo((t + 3) << 6, pB0, pB1);
      if (t + 1 < nt) compute(bufB, (t + 1) << 6);
      if (t + 2 < nt) writeAbFrom(bufA, pA0, pA1);
      __syncthreads();
    }
  } else {
    for (int t = 0; t < nt; ++t) {
      if (t) __syncthreads();
      stageAf(bufA, t << 6);
      __syncthreads();
      compute(bufA, t << 6);
    }
    __syncthreads();
  }

  // ---- epilogue: bias + act, write C (global) and Cs (LDS, for alphas) ----
#pragma unroll
  for (int mt = 0; mt < 2; ++mt) {
#pragma unroll
    for (int g = 0; g < 4; ++g) {
      int colg = nb + g * 16 + l15;
      float bv = bias ? bias[colg] : 0.f;
#pragma unroll
      for (int r = 0; r < 4; ++r) {
        int rl = mb + mt * 16 + quad * 4 + r;
        int rowg = m0 + rl;
        float v = acc[mt][g][r] + bv;
        if (relu) v = fmaxf(v, 0.f);
        unsigned short bv16 = (unsigned short)f2bf(v);
        if (waSD) uni[rl * 132 + colg] = (short)bv16;
        if (rowg < M) Cb2[(size_t)rowg * HIDC + colg] = bv16;
      }
    }
  }

  if (waSD) {
    __syncthreads();
    int r = tid >> 2, jq = tid & 3;
    int row = m0 + r;
    float s0 = 0.f, s1 = 0.f, s2 = 0.f, s3 = 0.f;
    const unsigned* c32 = (const unsigned*)uni;   // stride 66 uints per row
#pragma unroll 8
    for (int c2 = 0; c2 < 64; ++c2) {
      unsigned u = c32[r * 66 + c2];
      float hx = __uint_as_float(u << 16);
      float hy = __uint_as_float(u & 0xffff0000u);
      const float* w0 = &s_wa[(c2 * 2) * 16 + jq * 4];
      s0 = fmaf(hx, w0[0], fmaf(hy, w0[16], s0));
      s1 = fmaf(hx, w0[1], fmaf(hy, w0[17], s1));
      s2 = fmaf(hx, w0[2], fmaf(hy, w0[18], s2));
      s3 = fmaf(hx, w0[3], fmaf(hy, w0[19], s3));
    }
    if (row < M) {
      float4 v4 = make_float4(s0, s1, s2, s3);
      if (jq < 2) ((float4*)aS)[(size_t)row * 2 + jq] = v4;
      else        ((float4*)aD)[(size_t)row * 2 + (jq - 2)] = v4;
    }
  }
}

// ---------------------------------------------------------------------------
// Fused GRU (v1 structure + fragment-order B): per block, 64 rows x ALL 512
// S-cols of [hb|mem]@Bt512^T (K=256, reg-staged LDS double buffer), then
// gates + GRU blend + mean-pool accumulation entirely in-register.
// ---------------------------------------------------------------------------
__global__ __launch_bounds__(512) void gru_fused(
    const unsigned short* __restrict__ hb, const float* __restrict__ mem,
    const short* __restrict__ Bt512,
    const float* __restrict__ bI, const float* __restrict__ bH,
    const int* __restrict__ batch, float* __restrict__ pooled,
    float* __restrict__ cnt, int N)
{
  __shared__ short As[2 * 64 * 64];   // double buffer, 16 KB
  short* bufA = As;
  short* bufB = As + 64 * 64;

  const int tid = threadIdx.x;
  const int m0 = blockIdx.x * 64;
  const int wid = tid >> 6, lane = tid & 63;
  const int l15 = lane & 15, quad = lane >> 4;
  const int wm = wid & 1, wn = wid >> 1;     // 2 m-slices x 4 n-slices
  const int mb = wm * 32;

  floatx4 acc[2][8];
#pragma unroll
  for (int a = 0; a < 2; ++a)
#pragma unroll
    for (int g = 0; g < 8; ++g) acc[a][g] = (floatx4){0.f, 0.f, 0.f, 0.f};

  // staging: 64 rows x 64 k-shorts = 4096 shorts; 1 slot of 16B per thread
  const int r0 = tid >> 3, j0 = tid & 7;
  short8 pr;
  auto loadA = [&](int kb) {
    int row = m0 + r0; if (row >= N) row = N - 1;
    if (kb < 128) {
      pr = *(const short8*)&hb[(size_t)row * 128 + kb + (j0 << 3)];
    } else {
      const float4* m4 = (const float4*)(mem + (size_t)row * 128 + (kb - 128) + (j0 << 3));
      float4 a = m4[0], b = m4[1];
      short8 p;
      p[0] = f2bf(a.x); p[1] = f2bf(a.y); p[2] = f2bf(a.z); p[3] = f2bf(a.w);
      p[4] = f2bf(b.x); p[5] = f2bf(b.y); p[6] = f2bf(b.z); p[7] = f2bf(b.w);
      pr = p;
    }
  };
  auto writeA = [&](short* buf) {
    *(short8*)&buf[r0 * 64 + ((j0 ^ (r0 & 7)) << 3)] = pr;
  };
  auto compute = [&](const short* buf, int kb) {
    const int rr0 = mb + l15, rr1 = mb + 16 + l15;
    const int rx = rr0 & 7;
    const int kb64 = kb >> 6;
#pragma unroll
    for (int kk = 0; kk < 2; ++kk) {
      int c = kk * 4 + quad;
      int cs = (c ^ rx) << 3;
      short8 a0 = *(const short8*)&buf[rr0 * 64 + cs];
      short8 a1 = *(const short8*)&buf[rr1 * 64 + cs];
#pragma unroll
      for (int g = 0; g < 8; ++g) {
        // gate (g>>1), output col16 = (g>>1)*8 + wn*2 + (g&1)
        int col16 = ((g >> 1) << 3) + (wn << 1) + (g & 1);
        int frag = (col16 * 4 + kb64) * 2 + kk;
        short8 b = *(const short8*)&Bt512[(size_t)frag * 512 + lane * 8];
        acc[0][g] = __builtin_amdgcn_mfma_f32_16x16x32_bf16(a0, b, acc[0][g], 0, 0, 0);
        acc[1][g] = __builtin_amdgcn_mfma_f32_16x16x32_bf16(a1, b, acc[1][g], 0, 0, 0);
      }
    }
  };

  // K loop: 4 steps, double-buffered
  loadA(0);
  writeA(bufA);
  __syncthreads();
  for (int t = 0; t < 4; ++t) {
    short* cur = (t & 1) ? bufB : bufA;
    short* nxt = (t & 1) ? bufA : bufB;
    if (t < 3) loadA((t + 1) << 6);
    compute(cur, t << 6);
    if (t < 3) writeA(nxt);
    __syncthreads();
  }

  // ---- epilogue: gates + blend + pooling ----------------------------------
  int nlast = (m0 + 63 < N) ? (m0 + 63) : (N - 1);
  const bool unif = (batch[m0] == batch[nlast]);
  const int bg = batch[m0];

#pragma unroll
  for (int sub = 0; sub < 2; ++sub) {
    const int c = wn * 32 + sub * 16 + l15;
    const float bI0 = bI[c],       bH0 = bH[c];
    const float bI1 = bI[128 + c], bH1 = bH[128 + c];
    const float bI2 = bI[256 + c], bH2 = bH[256 + c];
    float pv = 0.f;
#pragma unroll
    for (int mt = 0; mt < 2; ++mt) {
#pragma unroll
      for (int r = 0; r < 4; ++r) {
        int row = m0 + mb + mt * 16 + quad * 4 + r;
        bool v = (row < N);
        int rowc = v ? row : (N - 1);
        float sr  = acc[mt][0 + sub][r] + bI0 + bH0;
        float sz  = acc[mt][2 + sub][r] + bI1 + bH1;
        float gin = acc[mt][4 + sub][r] + bI2;
        float ghn = acc[mt][6 + sub][r] + bH2;
        float rg = 1.f / (1.f + __expf(-sr));
        float zg = 1.f / (1.f + __expf(-sz));
        float ncv = tanhf(gin + rg * ghn);
        float val = (1.f - zg) * ncv + zg * mem[(size_t)rowc * 128 + c];
        if (!v) val = 0.f;
        if (unif) {
          pv += val;
        } else if (v) {
          atomicAdd(&pooled[(size_t)batch[row] * 128 + c], val);
          if (wn == 0 && l15 == 0 && sub == 0)
            atomicAdd(&cnt[batch[row]], 1.f);
        }
      }
    }
    if (unif) {
      pv += __shfl_xor(pv, 16);
      pv += __shfl_xor(pv, 32);
      if (quad == 0) atomicAdd(&pooled[(size_t)bg * 128 + c], pv);
    }
  }
  if (unif && tid == 0) atomicAdd(&cnt[bg], (float)(nlast - m0 + 1));
}

// ---------------------------------------------------------------------------
// CSR build
// ---------------------------------------------------------------------------
__global__ void hist_kernel(const int* __restrict__ ei, int* __restrict__ deg, int E, int N)
{
  int i = blockIdx.x * 256 + threadIdx.x;
  if (i >= E + N) return;
  int dst = (i < E) ? ei[E + i] : (i - E);
  atomicAdd(&deg[dst], 1);
}

__global__ __launch_bounds__(1024) void scan1_kernel(
    const int* __restrict__ deg, int* __restrict__ rowptr,
    int* __restrict__ bsum, int N)
{
  __shared__ int sd[1024];
  int i = blockIdx.x * 1024 + threadIdx.x;
  int v = (i < N) ? deg[i] : 0;
  sd[threadIdx.x] = v;
  __syncthreads();
  for (int off = 1; off < 1024; off <<= 1) {
    int t = (threadIdx.x >= off) ? sd[threadIdx.x - off] : 0;
    __syncthreads();
    sd[threadIdx.x] += t;
    __syncthreads();
  }
  if (i < N) rowptr[i] = sd[threadIdx.x] - v;
  if (threadIdx.x == 1023) bsum[blockIdx.x] = sd[1023];
}

__global__ __launch_bounds__(64) void scan2_kernel(int* __restrict__ bsum, int nb)
{
  int lane = threadIdx.x;
  int v = (lane < nb) ? bsum[lane] : 0;
  int incl = v;
  for (int off = 1; off < 64; off <<= 1) {
    int t = __shfl_up(incl, off);
    if (lane >= off) incl += t;
  }
  if (lane < nb) bsum[lane] = incl - v;
}

__global__ void scatter_kernel(const int* __restrict__ ei, const int* __restrict__ rowptr,
                               const int* __restrict__ bsum, int* __restrict__ cursor,
                               int* __restrict__ csr_src, int E, int N)
{
  int i = blockIdx.x * 256 + threadIdx.x;
  if (i >= E + N) return;
  int src, dst;
  if (i < E) { src = ei[i]; dst = ei[E + i]; }
  else { src = i - E; dst = i - E; }
  int pos = rowptr[dst] + bsum[dst >> 10] + atomicAdd(&cursor[dst], 1);
  csr_src[pos] = src;
}

// ---------------------------------------------------------------------------
// GAT aggregation v6 (+lazy rowptr correction): one wave per dst.
// ---------------------------------------------------------------------------
#define PKX(acc, p) asm("v_pk_fma_f32 %0, %2, %1, %0 op_sel:[0,0,0] op_sel_hi:[1,0,1]" \
                        : "+v"(acc) : "v"(hxy), "v"(p))
#define PKY(acc, p) asm("v_pk_fma_f32 %0, %2, %1, %0 op_sel:[0,1,0] op_sel_hi:[1,1,1]" \
                        : "+v"(acc) : "v"(hxy), "v"(p))

__global__ __launch_bounds__(256, 8) void gat_agg6(
    const unsigned short* __restrict__ hb, const int* __restrict__ rowptr,
    const int* __restrict__ bsum, const int* __restrict__ csr_src,
    const float* __restrict__ aS, const float* __restrict__ aD,
    unsigned short* __restrict__ agg, int N, int EN)
{
  __shared__ float s_p[4][48][8];
  __shared__ int   s_src[4][48];
  const int wid = threadIdx.x >> 6;
  const int lane = threadIdx.x & 63;
  const int dst = blockIdx.x * 4 + wid;
  if (dst >= N) return;
  const int el = lane >> 3, hh = lane & 7;
  const int start = rowptr[dst] + bsum[dst >> 10];
  const int endp = (dst + 1 < N) ? (rowptr[dst + 1] + bsum[(dst + 1) >> 10]) : EN;
  const int deg = endp - start;
  const float adh = aD[(size_t)dst * 8 + hh];
  const int ng = (deg < MAXI * 8) ? ((deg + 7) >> 3) : MAXI;

  float m = -1e30f;
  for (int i = 0; i < ng; ++i) {
    int e = i * 8 + el;
    int s = 0; float v = -1e30f;
    if (e < deg) {
      s = csr_src[start + e];
      v = aS[(size_t)s * 8 + hh] + adh;
      v = (v > 0.f) ? v : 0.2f * v;
    }
    if (hh == 0) s_src[wid][e] = s;
    s_p[wid][e][hh] = v;
    m = fmaxf(m, v);
  }
  for (int e0 = MAXI * 8; e0 < deg; e0 += 8) {
    int e = e0 + el;
    if (e < deg) {
      int s = csr_src[start + e];
      float v = aS[(size_t)s * 8 + hh] + adh;
      v = (v > 0.f) ? v : 0.2f * v;
      m = fmaxf(m, v);
    }
  }

  const unsigned* hb32 = (const unsigned*)hb;
  unsigned hv[8];
  {
    int4 sa = *(const int4*)&s_src[wid][0];
    int4 sb = *(const int4*)&s_src[wid][4];
    hv[0] = hb32[(unsigned)sa.x * 64 + lane];
    hv[1] = hb32[(unsigned)sa.y * 64 + lane];
    hv[2] = hb32[(unsigned)sa.z * 64 + lane];
    hv[3] = hb32[(unsigned)sa.w * 64 + lane];
    hv[4] = hb32[(unsigned)sb.x * 64 + lane];
    hv[5] = hb32[(unsigned)sb.y * 64 + lane];
    hv[6] = hb32[(unsigned)sb.z * 64 + lane];
    hv[7] = hb32[(unsigned)sb.w * 64 + lane];
  }

  m = fmaxf(m, __shfl_xor(m, 8));
  m = fmaxf(m, __shfl_xor(m, 16));
  m = fmaxf(m, __shfl_xor(m, 32));

  float dsum = 0.f;
  for (int i = 0; i < ng; ++i) {
    int e = i * 8 + el;
    float v = s_p[wid][e][hh];
    float p = (v > -1e29f) ? __expf(v - m) : 0.f;
    dsum += p;
    s_p[wid][e][hh] = p;
  }

  floatx2 axp[4], ayp[4];
#pragma unroll
  for (int j = 0; j < 4; ++j) {
    axp[j] = (floatx2){0.f, 0.f};
    ayp[j] = (floatx2){0.f, 0.f};
  }

  for (int i = 0; i < ng; ++i) {
    unsigned hn[8];
    if (i + 1 < ng) {
      int4 sa = *(const int4*)&s_src[wid][(i + 1) * 8];
      int4 sb = *(const int4*)&s_src[wid][(i + 1) * 8 + 4];
      hn[0] = hb32[(unsigned)sa.x * 64 + lane];
      hn[1] = hb32[(unsigned)sa.y * 64 + lane];
      hn[2] = hb32[(unsigned)sa.z * 64 + lane];
      hn[3] = hb32[(unsigned)sa.w * 64 + lane];
      hn[4] = hb32[(unsigned)sb.x * 64 + lane];
      hn[5] = hb32[(unsigned)sb.y * 64 + lane];
      hn[6] = hb32[(unsigned)sb.z * 64 + lane];
      hn[7] = hb32[(unsigned)sb.w * 64 + lane];
    }
#pragma unroll
    for (int ee = 0; ee < 8; ++ee) {
      unsigned u = hv[ee];
      floatx2 hxy;
      hxy[0] = __uint_as_float(u << 16);
      hxy[1] = __uint_as_float(u & 0xffff0000u);
      floatx4 pA = *(const floatx4*)&s_p[wid][i * 8 + ee][0];
      floatx4 pB = *(const floatx4*)&s_p[wid][i * 8 + ee][4];
      floatx2 p0 = pA.lo, p1 = pA.hi, p2 = pB.lo, p3 = pB.hi;
      PKX(axp[0], p0); PKY(ayp[0], p0);
      PKX(axp[1], p1); PKY(ayp[1], p1);
      PKX(axp[2], p2); PKY(ayp[2], p2);
      PKX(axp[3], p3); PKY(ayp[3], p3);
    }
    if (i + 1 < ng) {
#pragma unroll
      for (int q = 0; q < 8; ++q) hv[q] = hn[q];
    }
  }

  const int c2 = lane * 2;
  for (int e0 = MAXI * 8; e0 < deg; e0 += 8) {
    int e = e0 + el;
    float p = 0.f; int s = 0;
    if (e < deg) {
      s = csr_src[start + e];
      float v = aS[(size_t)s * 8 + hh] + adh;
      v = (v > 0.f) ? v : 0.2f * v;
      p = __expf(v - m);
    }
    dsum += p;
    int cnt = deg - e0; if (cnt > 8) cnt = 8;
    for (int ee = 0; ee < cnt; ++ee) {
      int se = __shfl(s, ee * 8);
      unsigned u = *(const unsigned*)&hb[(size_t)se * 128 + c2];
      float hx = __uint_as_float(u << 16);
      float hy = __uint_as_float(u & 0xffff0000u);
#pragma unroll
      for (int q = 0; q < 8; ++q) {
        float pq = __shfl(p, ee * 8 + q);
        axp[q >> 1][q & 1] = fmaf(pq, hx, axp[q >> 1][q & 1]);
        ayp[q >> 1][q & 1] = fmaf(pq, hy, ayp[q >> 1][q & 1]);
      }
    }
  }

  dsum += __shfl_xor(dsum, 8);
  dsum += __shfl_xor(dsum, 16);
  dsum += __shfl_xor(dsum, 32);
  float inv = 1.f / (dsum + 1e-16f);

#pragma unroll
  for (int q = 0; q < 8; ++q) {
    float invq = __shfl(inv, q);
    float ax = axp[q >> 1][q & 1] * invq;
    float ay = ayp[q >> 1][q & 1] * invq;
    unsigned pk = ((unsigned)(unsigned short)f2bf(ay) << 16) |
                  (unsigned)(unsigned short)f2bf(ax);
    *(unsigned*)&agg[(size_t)dst * 1024 + q * 128 + c2] = pk;
  }
}

// ---------------------------------------------------------------------------
// finalize pooled, classifier MLP, softmax
// ---------------------------------------------------------------------------
__global__ __launch_bounds__(64) void classifier_kernel(
    float* __restrict__ pooled, const float* __restrict__ cnt,
    const float* __restrict__ c1W, const float* __restrict__ c1b,
    const float* __restrict__ c2W, const float* __restrict__ c2b,
    float* __restrict__ logits, float* __restrict__ preds)
{
  int g = blockIdx.x, j = threadIdx.x;
  __shared__ float sp[128];
  __shared__ float hid[64];
  __shared__ float lg[3];
  float invc = 1.f / fmaxf(cnt[g], 1.f);
  float p0 = pooled[(size_t)g * 128 + j] * invc;
  float p1 = pooled[(size_t)g * 128 + 64 + j] * invc;
  pooled[(size_t)g * 128 + j] = p0;
  pooled[(size_t)g * 128 + 64 + j] = p1;
  sp[j] = p0; sp[j + 64] = p1;
  __syncthreads();
  float a = c1b[j];
#pragma unroll
  for (int k = 0; k < 128; ++k) a = fmaf(sp[k], c1W[k * 64 + j], a);
  hid[j] = fmaxf(a, 0.f);
  __syncthreads();
  if (j < NCLS) {
    float t = c2b[j];
#pragma unroll
    for (int k = 0; k < 64; ++k) t = fmaf(hid[k], c2W[k * NCLS + j], t);
    logits[(size_t)g * NCLS + j] = t;
    lg[j] = t;
  }
  __syncthreads();
  if (j < NCLS) {
    float mx = fmaxf(lg[0], fmaxf(lg[1], lg[2]));
    float e0 = __expf(lg[0] - mx), e1 = __expf(lg[1] - mx), e2 = __expf(lg[2] - mx);
    float mine = (j == 0) ? e0 : ((j == 1) ? e1 : e2);
    preds[(size_t)g * NCLS + j] = mine / (e0 + e1 + e2);
  }
}

// ---------------------------------------------------------------------------
extern "C" void kernel_launch(void* const* d_in, const int* in_sizes, int n_in,
                              void* d_out, int out_size, void* d_ws, size_t ws_size,
                              hipStream_t stream)
{
  const float* x       = (const float*)d_in[0];
  const int*   ei      = (const int*)d_in[1];
  const int*   batch   = (const int*)d_in[2];
  const float* memory  = (const float*)d_in[3];
  const float* enc_W   = (const float*)d_in[4];
  const float* enc_b   = (const float*)d_in[5];
  const float* gat_W   = (const float*)d_in[6];   // [NL,128,1024]
  const float* att_src = (const float*)d_in[7];
  const float* att_dst = (const float*)d_in[8];
  const float* gat_b   = (const float*)d_in[9];
  const float* W_ih    = (const float*)d_in[10];
  const float* W_hh    = (const float*)d_in[11];
  const float* b_ih    = (const float*)d_in[12];
  const float* b_hh    = (const float*)d_in[13];
  const float* c1W     = (const float*)d_in[14];
  const float* c1b     = (const float*)d_in[15];
  const float* c2W     = (const float*)d_in[16];
  const float* c2b     = (const float*)d_in[17];

  const int N = in_sizes[0] / HIDC;
  const int E = in_sizes[1] / 2;
  const int EN = E + N;
  const int NB = (N + 1023) / 1024;

  char* ws = (char*)d_ws;
  size_t off = 0;
  auto alloc = [&](size_t bytes) -> void* {
    void* p = ws + off;
    off += (bytes + 255) & ~(size_t)255;
    return p;
  };
  unsigned short* hb0 = (unsigned short*)alloc((size_t)N * HIDC * 2);
  unsigned short* hb1 = (unsigned short*)alloc((size_t)N * HIDC * 2);
  unsigned short* agg = (unsigned short*)alloc((size_t)N * 1024 * 2);
  float* aS     = (float*)alloc((size_t)N * NHEAD * 4);
  float* aD     = (float*)alloc((size_t)N * NHEAD * 4);
  short* encT   = (short*)alloc((size_t)128 * 128 * 2);
  short* Wp     = (short*)alloc((size_t)NLAY * 131072 * 2);
  float* waSD   = (float*)alloc((size_t)NLAY * 2048 * 4);
  short* Bt512  = (short*)alloc((size_t)512 * 256 * 2);
  int*   rowptr = (int*)alloc((size_t)(N + 1) * 4);
  size_t zoff0 = off;
  int*   cursor = (int*)alloc((size_t)N * 4);
  int*   degtmp = (int*)alloc((size_t)N * 4);
  size_t zbytes = off - zoff0;
  int*   bsum   = (int*)alloc(64 * 4);
  int*   csr    = (int*)alloc((size_t)EN * 4);
  float* cntbuf = (float*)alloc(64 * 4);

  float* out_logits = (float*)d_out;
  float* out_pooled = (float*)d_out + NGRAPH * NCLS;
  float* out_preds  = (float*)d_out + NGRAPH * NCLS + NGRAPH * HIDC;

  hipMemsetAsync(cursor, 0, zbytes, stream);

  // fused prep: weights (fragment-order B) + d_out/cnt zeroing (one dispatch)
  {
    int total = 16384 + NLAY * 131072 + 512 * 256 + (out_size + 64) + NLAY * 2048;
    prep_kernel<<<(total + 255) / 256, 256, 0, stream>>>(
        enc_W, encT, gat_W, Wp, W_ih, W_hh, Bt512, att_src, att_dst, waSD,
        (float*)d_out, out_size, cntbuf);
  }

  // CSR build
  hist_kernel<<<(EN + 255) / 256, 256, 0, stream>>>(ei, degtmp, E, N);
  scan1_kernel<<<NB, 1024, 0, stream>>>(degtmp, rowptr, bsum, N);
  scan2_kernel<<<1, 64, 0, stream>>>(bsum, NB);
  scatter_kernel<<<(EN + 255) / 256, 256, 0, stream>>>(ei, rowptr, bsum, cursor,
                                                       csr, E, N);

  const int MB = (N + 127) / 128;

  // encoder: hb0 = bf16(relu(x @ enc_W + enc_b)) + fused alphas for layer 0
  mm_gat<<<MB, 512, 0, stream>>>(nullptr, x, encT, enc_b, hb0,
                                 waSD, aS, aD, N, 128, 1);

  unsigned short* hbcur = hb0;
  unsigned short* hbnxt = hb1;
  for (int l = 0; l < NLAY; ++l) {
    gat_agg6<<<(N + 3) / 4, 256, 0, stream>>>(hbcur, rowptr, bsum, csr, aS, aD,
                                              agg, N, EN);
    const float* wnext = (l < NLAY - 1) ? (waSD + (size_t)(l + 1) * 2048) : nullptr;
    mm_gat<<<MB, 512, 0, stream>>>(agg, nullptr, Wp + (size_t)l * 131072,
                                   gat_b + (size_t)l * HIDC, hbnxt,
                                   wnext, aS, aD, N, 1024, (l < NLAY - 1) ? 1 : 0);
    unsigned short* tb = hbcur; hbcur = hbnxt; hbnxt = tb;
  }

  // fused GRU: matmul + gates + blend + mean-pool in one dispatch
  gru_fused<<<(N + 63) / 64, 512, 0, stream>>>(hbcur, memory, Bt512, b_ih, b_hh,
                                               batch, out_pooled, cntbuf, N);

  // classifier
  classifier_kernel<<<NGRAPH, 64, 0, stream>>>(out_pooled, cntbuf, c1W, c1b, c2W, c2b,
                                               out_logits, out_preds);
}

// Round 16
// 637.335 us; speedup vs baseline: 1.0994x; 1.0170x over previous
//
#include <hip/hip_runtime.h>
#include <cstdint>
#include <cstddef>

#define HIDC 128
#define NHEAD 8
#define NLAY 3
#define NGRAPH 64
#define NCLS 3
#define MAXI 6   // fast path deg <= 48

typedef __attribute__((ext_vector_type(8))) short short8;
typedef __attribute__((ext_vector_type(4))) float floatx4;
typedef __attribute__((ext_vector_type(2))) float floatx2;

__device__ inline short f2bf(float x) {
  unsigned u = __float_as_uint(x);
  unsigned r = (u + 0x7fff + ((u >> 16) & 1)) >> 16;   // RNE
  return (short)r;
}
__device__ inline float bf2f(unsigned short u) {
  return __uint_as_float(((unsigned)u) << 16);
}

// ---------------------------------------------------------------------------
// B matrices are stored in MFMA-FRAGMENT order:
//   Bf[frag*512 + lane*8 + j]  ==  B[col16*16 + (lane&15)][kb64*64 + kk*32 + (lane>>4)*8 + j]
//   frag = (col16 * (K/64) + kb64) * 2 + kk
// so each wave's B operand is ONE contiguous 1KB coalesced load.
// ---------------------------------------------------------------------------

// ---------------------------------------------------------------------------
// Unified prep kernel: encT/Wp/Bt512 built in fragment order, waSD dots,
// d_out + cnt zeroing.
// ---------------------------------------------------------------------------
__global__ __launch_bounds__(256) void prep_kernel(
    const float* __restrict__ enc_W, short* __restrict__ encT,
    const float* __restrict__ gat_W, short* __restrict__ Wp,
    const float* __restrict__ W_ih, const float* __restrict__ W_hh,
    short* __restrict__ Bt512,
    const float* __restrict__ att_src, const float* __restrict__ att_dst,
    float* __restrict__ waSD,
    float* __restrict__ d_out_f, int out_size, float* __restrict__ cnt)
{
  int idx = blockIdx.x * 256 + threadIdx.x;

  // encT: K=128, 8 col16 x 2 kb64 x 2 kk = 32 frags x 512 shorts
  if (idx < 16384) {
    int frag = idx >> 9, rem = idx & 511;
    int lane = rem >> 3, j = rem & 7;
    int col16 = frag >> 2, kb64 = (frag >> 1) & 1, kk = frag & 1;
    int col = col16 * 16 + (lane & 15);
    int k = kb64 * 64 + kk * 32 + ((lane >> 4) << 3) + j;
    encT[idx] = f2bf(enc_W[(size_t)k * 128 + col]);
    return;
  }
  idx -= 16384;

  // Wp: per layer K=1024, 8 col16 x 16 kb64 x 2 kk = 256 frags x 512 shorts
  if (idx < NLAY * 131072) {
    int l = idx >> 17, rem17 = idx & 131071;
    int frag = rem17 >> 9, rem = rem17 & 511;
    int lane = rem >> 3, j = rem & 7;
    int col16 = frag >> 5, kb64 = (frag >> 1) & 15, kk = frag & 1;
    int cc = col16 * 16 + (lane & 15);
    int k1024 = kb64 * 64 + kk * 32 + ((lane >> 4) << 3) + j;
    int hh = k1024 >> 7, k = k1024 & 127;
    Wp[idx] = f2bf(gat_W[(size_t)l * 131072 + (size_t)k * 1024 + hh * 128 + cc]
                   * 0.125f);
    return;
  }
  idx -= NLAY * 131072;

  // Bt512: K=256, 32 col16 x 4 kb64 x 2 kk = 256 frags x 512 shorts
  if (idx < 512 * 256) {
    int frag = idx >> 9, rem = idx & 511;
    int lane = rem >> 3, j = rem & 7;
    int col16 = frag >> 3, kb64 = (frag >> 1) & 3, kk = frag & 1;
    int col = col16 * 16 + (lane & 15);
    int k = kb64 * 64 + kk * 32 + ((lane >> 4) << 3) + j;
    float v;
    if (k < 128) {
      v = (col < 384) ? W_ih[(size_t)col * 128 + k] : 0.f;
    } else {
      int k2 = k - 128;
      if (col < 256) v = W_hh[(size_t)col * 128 + k2];
      else if (col < 384) v = 0.f;
      else v = W_hh[(size_t)(col - 128) * 128 + k2];
    }
    Bt512[idx] = f2bf(v);
    return;
  }
  idx -= 512 * 256;

  if (idx < out_size + 64) {
    if (idx < out_size) d_out_f[idx] = 0.f;
    else cnt[idx - out_size] = 0.f;
    return;
  }
  idx -= out_size + 64;

  if (idx < NLAY * 2048) {
    int l = idx / 2048, rem = idx - l * 2048;
    int k = rem >> 4, j16 = rem & 15;
    int hh = j16 & 7;
    const float* a = ((j16 < 8) ? att_src : att_dst) + (size_t)l * 1024 + hh * 128;
    const float* w = gat_W + (size_t)l * 131072 + (size_t)k * 1024 + hh * 128;
    float s = 0.f;
    for (int cc = 0; cc < 128; ++cc) s += w[cc] * a[cc];
    waSD[(size_t)l * 2048 + rem] = s;
  }
}

// ---------------------------------------------------------------------------
// Unified GAT-chain matmul v5: C[M,128] = act(A @ B + bias).
//   A: bf16[M,K] (Ab) reg-staged 2-DEEP prefetch pipeline (load t+2 ->
//      compute t -> write t+1 -> barrier; extra tile lives in registers;
//      K=1024 so nt=16 even, statically 2-unrolled), or
//      fp32[M,K] (Af) reg-staged with conversion (unpipelined, small K).
//   B in FRAGMENT order -> each wave B-load is one coalesced 1KB read.
//   BM=128 rows/block, 512 threads (8 waves: 4 m-slices x 2 n-slices).
//   LDS A-tiles XOR-swizzled (chunk ^= row&7) on BOTH write and read.
//   Optional fused alpha epilogue via Cs staged in the (reused) A LDS.
// ---------------------------------------------------------------------------
__global__ __launch_bounds__(512) void mm_gat(
    const unsigned short* __restrict__ Ab, const float* __restrict__ Af,
    const short* __restrict__ Bt, const float* __restrict__ bias,
    unsigned short* __restrict__ Cb2,
    const float* __restrict__ waSD, float* __restrict__ aS,
    float* __restrict__ aD, int M, int K, int relu)
{
  __shared__ short uni[128 * 132];   // 2 A-buffers (2x8192 shorts) / Cs (stride 132)
  __shared__ float s_wa[2048];
  short* bufA = uni;
  short* bufB = uni + 128 * 64;

  const int tid = threadIdx.x;
  const int m0 = blockIdx.x * 128;
  const int wid = tid >> 6, lane = tid & 63;
  const int l15 = lane & 15, quad = lane >> 4;
  const int wm = wid & 3, wn = wid >> 2;
  const int mb = wm * 32;
  const int nb = wn * 64;

  if (waSD) {
    for (int i = tid; i < 2048; i += 512) s_wa[i] = waSD[i];
  }

  floatx4 acc[2][4];
#pragma unroll
  for (int a = 0; a < 2; ++a)
#pragma unroll
    for (int g = 0; g < 4; ++g) acc[a][g] = (floatx4){0.f, 0.f, 0.f, 0.f};

  const int nt = K >> 6;

  // thread -> (row, chunk) mapping for staging: two slots per thread
  const int r0 = tid >> 3,        j0 = tid & 7;           // rows 0..63
  const int r1 = 64 + (tid >> 3), j1 = tid & 7;           // rows 64..127

  auto loadAbTo = [&](int kb, short8& q0, short8& q1) {
    int row0 = m0 + r0; if (row0 >= M) row0 = M - 1;
    int row1 = m0 + r1; if (row1 >= M) row1 = M - 1;
    q0 = *(const short8*)&Ab[(size_t)row0 * K + kb + (j0 << 3)];
    q1 = *(const short8*)&Ab[(size_t)row1 * K + kb + (j1 << 3)];
  };
  auto writeAbFrom = [&](short* buf, short8 q0, short8 q1) {
    *(short8*)&buf[r0 * 64 + ((j0 ^ (r0 & 7)) << 3)] = q0;
    *(short8*)&buf[r1 * 64 + ((j1 ^ (r1 & 7)) << 3)] = q1;
  };
  auto stageAf = [&](short* buf, int kb) {
#pragma unroll
    for (int c = 0; c < 2; ++c) {
      int id = c * 512 + tid;
      int r = id >> 3, j = id & 7;
      int row = m0 + r; if (row >= M) row = M - 1;
      const float4* m4 = (const float4*)(Af + (size_t)row * K + kb + (j << 3));
      float4 a = m4[0], b = m4[1];
      short8 p;
      p[0] = f2bf(a.x); p[1] = f2bf(a.y); p[2] = f2bf(a.z); p[3] = f2bf(a.w);
      p[4] = f2bf(b.x); p[5] = f2bf(b.y); p[6] = f2bf(b.z); p[7] = f2bf(b.w);
      *(short8*)&buf[r * 64 + ((j ^ (r & 7)) << 3)] = p;
    }
  };
  auto compute = [&](const short* buf, int kb) {
    const int rr0 = mb + l15, rr1 = mb + 16 + l15;
    const int rx = rr0 & 7;    // == rr1 & 7
    const int kb64 = kb >> 6;
#pragma unroll
    for (int kk = 0; kk < 2; ++kk) {
      int c = kk * 4 + quad;
      int cs = (c ^ rx) << 3;
      short8 a0 = *(const short8*)&buf[rr0 * 64 + cs];
      short8 a1 = *(const short8*)&buf[rr1 * 64 + cs];
#pragma unroll
      for (int g = 0; g < 4; ++g) {
        int col16 = (nb >> 4) + g;
        int frag = (col16 * nt + kb64) * 2 + kk;
        short8 b = *(const short8*)&Bt[(size_t)frag * 512 + lane * 8];
        acc[0][g] = __builtin_amdgcn_mfma_f32_16x16x32_bf16(a0, b, acc[0][g], 0, 0, 0);
        acc[1][g] = __builtin_amdgcn_mfma_f32_16x16x32_bf16(a1, b, acc[1][g], 0, 0, 0);
      }
    }
  };

  // ---- K loop -------------------------------------------------------------
  if (Ab) {
    // 2-deep prefetch, statically 2-unrolled (nt = 16, even):
    short8 pA0, pA1, pB0, pB1;
    loadAbTo(0, pA0, pA1);
    writeAbFrom(bufA, pA0, pA1);
    loadAbTo(64, pB0, pB1);
    __syncthreads();
    for (int t = 0; t < nt; t += 2) {
      if (t + 2 < nt) loadAbTo((t + 2) << 6, pA0, pA1);
      compute(bufA, t << 6);
      if (t + 1 < nt) writeAbFrom(bufB, pB0, pB1);
      __syncthreads();
      if (t + 3 < nt) loadAbTo((t + 3) << 6, pB0, pB1);
      if (t + 1 < nt) compute(bufB, (t + 1) << 6);
      if (t + 2 < nt) writeAbFrom(bufA, pA0, pA1);
      __syncthreads();
    }
  } else {
    for (int t = 0; t < nt; ++t) {
      if (t) __syncthreads();
      stageAf(bufA, t << 6);
      __syncthreads();
      compute(bufA, t << 6);
    }
    __syncthreads();
  }

  // ---- epilogue: bias + act, write C (global) and Cs (LDS, for alphas) ----
#pragma unroll
  for (int mt = 0; mt < 2; ++mt) {
#pragma unroll
    for (int g = 0; g < 4; ++g) {
      int colg = nb + g * 16 + l15;
      float bv = bias ? bias[colg] : 0.f;
#pragma unroll
      for (int r = 0; r < 4; ++r) {
        int rl = mb + mt * 16 + quad * 4 + r;
        int rowg = m0 + rl;
        float v = acc[mt][g][r] + bv;
        if (relu) v = fmaxf(v, 0.f);
        unsigned short bv16 = (unsigned short)f2bf(v);
        if (waSD) uni[rl * 132 + colg] = (short)bv16;
        if (rowg < M) Cb2[(size_t)rowg * HIDC + colg] = bv16;
      }
    }
  }

  if (waSD) {
    __syncthreads();
    int r = tid >> 2, jq = tid & 3;
    int row = m0 + r;
    float s0 = 0.f, s1 = 0.f, s2 = 0.f, s3 = 0.f;
    const unsigned* c32 = (const unsigned*)uni;   // stride 66 uints per row
#pragma unroll 8
    for (int c2 = 0; c2 < 64; ++c2) {
      unsigned u = c32[r * 66 + c2];
      float hx = __uint_as_float(u << 16);
      float hy = __uint_as_float(u & 0xffff0000u);
      const float* w0 = &s_wa[(c2 * 2) * 16 + jq * 4];
      s0 = fmaf(hx, w0[0], fmaf(hy, w0[16], s0));
      s1 = fmaf(hx, w0[1], fmaf(hy, w0[17], s1));
      s2 = fmaf(hx, w0[2], fmaf(hy, w0[18], s2));
      s3 = fmaf(hx, w0[3], fmaf(hy, w0[19], s3));
    }
    if (row < M) {
      float4 v4 = make_float4(s0, s1, s2, s3);
      if (jq < 2) ((float4*)aS)[(size_t)row * 2 + jq] = v4;
      else        ((float4*)aD)[(size_t)row * 2 + (jq - 2)] = v4;
    }
  }
}

// ---------------------------------------------------------------------------
// Fused GRU v2: fragment-order B + 2-DEEP prefetch pipeline (ported from
// mm_gat v5: load t+2 -> compute t -> write t+1 -> barrier; nt=4 even,
// statically 2-unrolled).  Per block, 64 rows x ALL 512 S-cols of
// [hb|mem]@Bt512^T (K=256), then gates + GRU blend + mean-pool in-register.
// ---------------------------------------------------------------------------
__global__ __launch_bounds__(512) void gru_fused(
    const unsigned short* __restrict__ hb, const float* __restrict__ mem,
    const short* __restrict__ Bt512,
    const float* __restrict__ bI, const float* __restrict__ bH,
    const int* __restrict__ batch, float* __restrict__ pooled,
    float* __restrict__ cnt, int N)
{
  __shared__ short As[2 * 64 * 64];   // double buffer, 16 KB
  short* bufA = As;
  short* bufB = As + 64 * 64;

  const int tid = threadIdx.x;
  const int m0 = blockIdx.x * 64;
  const int wid = tid >> 6, lane = tid & 63;
  const int l15 = lane & 15, quad = lane >> 4;
  const int wm = wid & 1, wn = wid >> 1;     // 2 m-slices x 4 n-slices
  const int mb = wm * 32;

  floatx4 acc[2][8];
#pragma unroll
  for (int a = 0; a < 2; ++a)
#pragma unroll
    for (int g = 0; g < 8; ++g) acc[a][g] = (floatx4){0.f, 0.f, 0.f, 0.f};

  // staging: 64 rows x 64 k-shorts = 4096 shorts; 1 slot of 16B per thread
  const int r0 = tid >> 3, j0 = tid & 7;
  auto loadATo = [&](int kb, short8& q) {
    int row = m0 + r0; if (row >= N) row = N - 1;
    if (kb < 128) {
      q = *(const short8*)&hb[(size_t)row * 128 + kb + (j0 << 3)];
    } else {
      const float4* m4 = (const float4*)(mem + (size_t)row * 128 + (kb - 128) + (j0 << 3));
      float4 a = m4[0], b = m4[1];
      short8 p;
      p[0] = f2bf(a.x); p[1] = f2bf(a.y); p[2] = f2bf(a.z); p[3] = f2bf(a.w);
      p[4] = f2bf(b.x); p[5] = f2bf(b.y); p[6] = f2bf(b.z); p[7] = f2bf(b.w);
      q = p;
    }
  };
  auto writeAFrom = [&](short* buf, short8 q) {
    *(short8*)&buf[r0 * 64 + ((j0 ^ (r0 & 7)) << 3)] = q;
  };
  auto compute = [&](const short* buf, int kb) {
    const int rr0 = mb + l15, rr1 = mb + 16 + l15;
    const int rx = rr0 & 7;
    const int kb64 = kb >> 6;
#pragma unroll
    for (int kk = 0; kk < 2; ++kk) {
      int c = kk * 4 + quad;
      int cs = (c ^ rx) << 3;
      short8 a0 = *(const short8*)&buf[rr0 * 64 + cs];
      short8 a1 = *(const short8*)&buf[rr1 * 64 + cs];
#pragma unroll
      for (int g = 0; g < 8; ++g) {
        // gate (g>>1), output col16 = (g>>1)*8 + wn*2 + (g&1)
        int col16 = ((g >> 1) << 3) + (wn << 1) + (g & 1);
        int frag = (col16 * 4 + kb64) * 2 + kk;
        short8 b = *(const short8*)&Bt512[(size_t)frag * 512 + lane * 8];
        acc[0][g] = __builtin_amdgcn_mfma_f32_16x16x32_bf16(a0, b, acc[0][g], 0, 0, 0);
        acc[1][g] = __builtin_amdgcn_mfma_f32_16x16x32_bf16(a1, b, acc[1][g], 0, 0, 0);
      }
    }
  };

  // K loop: 4 steps, 2-deep prefetch, statically 2-unrolled
  {
    short8 pA, pB;
    loadATo(0, pA);
    writeAFrom(bufA, pA);
    loadATo(64, pB);
    __syncthreads();
    for (int t = 0; t < 4; t += 2) {
      if (t + 2 < 4) loadATo((t + 2) << 6, pA);
      compute(bufA, t << 6);
      if (t + 1 < 4) writeAFrom(bufB, pB);
      __syncthreads();
      if (t + 3 < 4) loadATo((t + 3) << 6, pB);
      if (t + 1 < 4) compute(bufB, (t + 1) << 6);
      if (t + 2 < 4) writeAFrom(bufA, pA);
      __syncthreads();
    }
  }

  // ---- epilogue: gates + blend + pooling ----------------------------------
  int nlast = (m0 + 63 < N) ? (m0 + 63) : (N - 1);
  const bool unif = (batch[m0] == batch[nlast]);
  const int bg = batch[m0];

#pragma unroll
  for (int sub = 0; sub < 2; ++sub) {
    const int c = wn * 32 + sub * 16 + l15;
    const float bI0 = bI[c],       bH0 = bH[c];
    const float bI1 = bI[128 + c], bH1 = bH[128 + c];
    const float bI2 = bI[256 + c], bH2 = bH[256 + c];
    float pv = 0.f;
#pragma unroll
    for (int mt = 0; mt < 2; ++mt) {
#pragma unroll
      for (int r = 0; r < 4; ++r) {
        int row = m0 + mb + mt * 16 + quad * 4 + r;
        bool v = (row < N);
        int rowc = v ? row : (N - 1);
        float sr  = acc[mt][0 + sub][r] + bI0 + bH0;
        float sz  = acc[mt][2 + sub][r] + bI1 + bH1;
        float gin = acc[mt][4 + sub][r] + bI2;
        float ghn = acc[mt][6 + sub][r] + bH2;
        float rg = 1.f / (1.f + __expf(-sr));
        float zg = 1.f / (1.f + __expf(-sz));
        float ncv = tanhf(gin + rg * ghn);
        float val = (1.f - zg) * ncv + zg * mem[(size_t)rowc * 128 + c];
        if (!v) val = 0.f;
        if (unif) {
          pv += val;
        } else if (v) {
          atomicAdd(&pooled[(size_t)batch[row] * 128 + c], val);
          if (wn == 0 && l15 == 0 && sub == 0)
            atomicAdd(&cnt[batch[row]], 1.f);
        }
      }
    }
    if (unif) {
      pv += __shfl_xor(pv, 16);
      pv += __shfl_xor(pv, 32);
      if (quad == 0) atomicAdd(&pooled[(size_t)bg * 128 + c], pv);
    }
  }
  if (unif && tid == 0) atomicAdd(&cnt[bg], (float)(nlast - m0 + 1));
}

// ---------------------------------------------------------------------------
// CSR build
// ---------------------------------------------------------------------------
__global__ void hist_kernel(const int* __restrict__ ei, int* __restrict__ deg, int E, int N)
{
  int i = blockIdx.x * 256 + threadIdx.x;
  if (i >= E + N) return;
  int dst = (i < E) ? ei[E + i] : (i - E);
  atomicAdd(&deg[dst], 1);
}

__global__ __launch_bounds__(1024) void scan1_kernel(
    const int* __restrict__ deg, int* __restrict__ rowptr,
    int* __restrict__ bsum, int N)
{
  __shared__ int sd[1024];
  int i = blockIdx.x * 1024 + threadIdx.x;
  int v = (i < N) ? deg[i] : 0;
  sd[threadIdx.x] = v;
  __syncthreads();
  for (int off = 1; off < 1024; off <<= 1) {
    int t = (threadIdx.x >= off) ? sd[threadIdx.x - off] : 0;
    __syncthreads();
    sd[threadIdx.x] += t;
    __syncthreads();
  }
  if (i < N) rowptr[i] = sd[threadIdx.x] - v;
  if (threadIdx.x == 1023) bsum[blockIdx.x] = sd[1023];
}

__global__ __launch_bounds__(64) void scan2_kernel(int* __restrict__ bsum, int nb)
{
  int lane = threadIdx.x;
  int v = (lane < nb) ? bsum[lane] : 0;
  int incl = v;
  for (int off = 1; off < 64; off <<= 1) {
    int t = __shfl_up(incl, off);
    if (lane >= off) incl += t;
  }
  if (lane < nb) bsum[lane] = incl - v;
}

__global__ void scatter_kernel(const int* __restrict__ ei, const int* __restrict__ rowptr,
                               const int* __restrict__ bsum, int* __restrict__ cursor,
                               int* __restrict__ csr_src, int E, int N)
{
  int i = blockIdx.x * 256 + threadIdx.x;
  if (i >= E + N) return;
  int src, dst;
  if (i < E) { src = ei[i]; dst = ei[E + i]; }
  else { src = i - E; dst = i - E; }
  int pos = rowptr[dst] + bsum[dst >> 10] + atomicAdd(&cursor[dst], 1);
  csr_src[pos] = src;
}

// ---------------------------------------------------------------------------
// GAT aggregation v6 (+lazy rowptr correction): one wave per dst.
// ---------------------------------------------------------------------------
#define PKX(acc, p) asm("v_pk_fma_f32 %0, %2, %1, %0 op_sel:[0,0,0] op_sel_hi:[1,0,1]" \
                        : "+v"(acc) : "v"(hxy), "v"(p))
#define PKY(acc, p) asm("v_pk_fma_f32 %0, %2, %1, %0 op_sel:[0,1,0] op_sel_hi:[1,1,1]" \
                        : "+v"(acc) : "v"(hxy), "v"(p))

__global__ __launch_bounds__(256, 8) void gat_agg6(
    const unsigned short* __restrict__ hb, const int* __restrict__ rowptr,
    const int* __restrict__ bsum, const int* __restrict__ csr_src,
    const float* __restrict__ aS, const float* __restrict__ aD,
    unsigned short* __restrict__ agg, int N, int EN)
{
  __shared__ float s_p[4][48][8];
  __shared__ int   s_src[4][48];
  const int wid = threadIdx.x >> 6;
  const int lane = threadIdx.x & 63;
  const int dst = blockIdx.x * 4 + wid;
  if (dst >= N) return;
  const int el = lane >> 3, hh = lane & 7;
  const int start = rowptr[dst] + bsum[dst >> 10];
  const int endp = (dst + 1 < N) ? (rowptr[dst + 1] + bsum[(dst + 1) >> 10]) : EN;
  const int deg = endp - start;
  const float adh = aD[(size_t)dst * 8 + hh];
  const int ng = (deg < MAXI * 8) ? ((deg + 7) >> 3) : MAXI;

  float m = -1e30f;
  for (int i = 0; i < ng; ++i) {
    int e = i * 8 + el;
    int s = 0; float v = -1e30f;
    if (e < deg) {
      s = csr_src[start + e];
      v = aS[(size_t)s * 8 + hh] + adh;
      v = (v > 0.f) ? v : 0.2f * v;
    }
    if (hh == 0) s_src[wid][e] = s;
    s_p[wid][e][hh] = v;
    m = fmaxf(m, v);
  }
  for (int e0 = MAXI * 8; e0 < deg; e0 += 8) {
    int e = e0 + el;
    if (e < deg) {
      int s = csr_src[start + e];
      float v = aS[(size_t)s * 8 + hh] + adh;
      v = (v > 0.f) ? v : 0.2f * v;
      m = fmaxf(m, v);
    }
  }

  const unsigned* hb32 = (const unsigned*)hb;
  unsigned hv[8];
  {
    int4 sa = *(const int4*)&s_src[wid][0];
    int4 sb = *(const int4*)&s_src[wid][4];
    hv[0] = hb32[(unsigned)sa.x * 64 + lane];
    hv[1] = hb32[(unsigned)sa.y * 64 + lane];
    hv[2] = hb32[(unsigned)sa.z * 64 + lane];
    hv[3] = hb32[(unsigned)sa.w * 64 + lane];
    hv[4] = hb32[(unsigned)sb.x * 64 + lane];
    hv[5] = hb32[(unsigned)sb.y * 64 + lane];
    hv[6] = hb32[(unsigned)sb.z * 64 + lane];
    hv[7] = hb32[(unsigned)sb.w * 64 + lane];
  }

  m = fmaxf(m, __shfl_xor(m, 8));
  m = fmaxf(m, __shfl_xor(m, 16));
  m = fmaxf(m, __shfl_xor(m, 32));

  float dsum = 0.f;
  for (int i = 0; i < ng; ++i) {
    int e = i * 8 + el;
    float v = s_p[wid][e][hh];
    float p = (v > -1e29f) ? __expf(v - m) : 0.f;
    dsum += p;
    s_p[wid][e][hh] = p;
  }

  floatx2 axp[4], ayp[4];
#pragma unroll
  for (int j = 0; j < 4; ++j) {
    axp[j] = (floatx2){0.f, 0.f};
    ayp[j] = (floatx2){0.f, 0.f};
  }

  for (int i = 0; i < ng; ++i) {
    unsigned hn[8];
    if (i + 1 < ng) {
      int4 sa = *(const int4*)&s_src[wid][(i + 1) * 8];
      int4 sb = *(const int4*)&s_src[wid][(i + 1) * 8 + 4];
      hn[0] = hb32[(unsigned)sa.x * 64 + lane];
      hn[1] = hb32[(unsigned)sa.y * 64 + lane];
      hn[2] = hb32[(unsigned)sa.z * 64 + lane];
      hn[3] = hb32[(unsigned)sa.w * 64 + lane];
      hn[4] = hb32[(unsigned)sb.x * 64 + lane];
      hn[5] = hb32[(unsigned)sb.y * 64 + lane];
      hn[6] = hb32[(unsigned)sb.z * 64 + lane];
      hn[7] = hb32[(unsigned)sb.w * 64 + lane];
    }
#pragma unroll
    for (int ee = 0; ee < 8; ++ee) {
      unsigned u = hv[ee];
      floatx2 hxy;
      hxy[0] = __uint_as_float(u << 16);
      hxy[1] = __uint_as_float(u & 0xffff0000u);
      floatx4 pA = *(const floatx4*)&s_p[wid][i * 8 + ee][0];
      floatx4 pB = *(const floatx4*)&s_p[wid][i * 8 + ee][4];
      floatx2 p0 = pA.lo, p1 = pA.hi, p2 = pB.lo, p3 = pB.hi;
      PKX(axp[0], p0); PKY(ayp[0], p0);
      PKX(axp[1], p1); PKY(ayp[1], p1);
      PKX(axp[2], p2); PKY(ayp[2], p2);
      PKX(axp[3], p3); PKY(ayp[3], p3);
    }
    if (i + 1 < ng) {
#pragma unroll
      for (int q = 0; q < 8; ++q) hv[q] = hn[q];
    }
  }

  const int c2 = lane * 2;
  for (int e0 = MAXI * 8; e0 < deg; e0 += 8) {
    int e = e0 + el;
    float p = 0.f; int s = 0;
    if (e < deg) {
      s = csr_src[start + e];
      float v = aS[(size_t)s * 8 + hh] + adh;
      v = (v > 0.f) ? v : 0.2f * v;
      p = __expf(v - m);
    }
    dsum += p;
    int cnt = deg - e0; if (cnt > 8) cnt = 8;
    for (int ee = 0; ee < cnt; ++ee) {
      int se = __shfl(s, ee * 8);
      unsigned u = *(const unsigned*)&hb[(size_t)se * 128 + c2];
      float hx = __uint_as_float(u << 16);
      float hy = __uint_as_float(u & 0xffff0000u);
#pragma unroll
      for (int q = 0; q < 8; ++q) {
        float pq = __shfl(p, ee * 8 + q);
        axp[q >> 1][q & 1] = fmaf(pq, hx, axp[q >> 1][q & 1]);
        ayp[q >> 1][q & 1] = fmaf(pq, hy, ayp[q >> 1][q & 1]);
      }
    }
  }

  dsum += __shfl_xor(dsum, 8);
  dsum += __shfl_xor(dsum, 16);
  dsum += __shfl_xor(dsum, 32);
  float inv = 1.f / (dsum + 1e-16f);

#pragma unroll
  for (int q = 0; q < 8; ++q) {
    float invq = __shfl(inv, q);
    float ax = axp[q >> 1][q & 1] * invq;
    float ay = ayp[q >> 1][q & 1] * invq;
    unsigned pk = ((unsigned)(unsigned short)f2bf(ay) << 16) |
                  (unsigned)(unsigned short)f2bf(ax);
    *(unsigned*)&agg[(size_t)dst * 1024 + q * 128 + c2] = pk;
  }
}

// ---------------------------------------------------------------------------
// finalize pooled, classifier MLP, softmax
// ---------------------------------------------------------------------------
__global__ __launch_bounds__(64) void classifier_kernel(
    float* __restrict__ pooled, const float* __restrict__ cnt,
    const float* __restrict__ c1W, const float* __restrict__ c1b,
    const float* __restrict__ c2W, const float* __restrict__ c2b,
    float* __restrict__ logits, float* __restrict__ preds)
{
  int g = blockIdx.x, j = threadIdx.x;
  __shared__ float sp[128];
  __shared__ float hid[64];
  __shared__ float lg[3];
  float invc = 1.f / fmaxf(cnt[g], 1.f);
  float p0 = pooled[(size_t)g * 128 + j] * invc;
  float p1 = pooled[(size_t)g * 128 + 64 + j] * invc;
  pooled[(size_t)g * 128 + j] = p0;
  pooled[(size_t)g * 128 + 64 + j] = p1;
  sp[j] = p0; sp[j + 64] = p1;
  __syncthreads();
  float a = c1b[j];
#pragma unroll
  for (int k = 0; k < 128; ++k) a = fmaf(sp[k], c1W[k * 64 + j], a);
  hid[j] = fmaxf(a, 0.f);
  __syncthreads();
  if (j < NCLS) {
    float t = c2b[j];
#pragma unroll
    for (int k = 0; k < 64; ++k) t = fmaf(hid[k], c2W[k * NCLS + j], t);
    logits[(size_t)g * NCLS + j] = t;
    lg[j] = t;
  }
  __syncthreads();
  if (j < NCLS) {
    float mx = fmaxf(lg[0], fmaxf(lg[1], lg[2]));
    float e0 = __expf(lg[0] - mx), e1 = __expf(lg[1] - mx), e2 = __expf(lg[2] - mx);
    float mine = (j == 0) ? e0 : ((j == 1) ? e1 : e2);
    preds[(size_t)g * NCLS + j] = mine / (e0 + e1 + e2);
  }
}

// ---------------------------------------------------------------------------
extern "C" void kernel_launch(void* const* d_in, const int* in_sizes, int n_in,
                              void* d_out, int out_size, void* d_ws, size_t ws_size,
                              hipStream_t stream)
{
  const float* x       = (const float*)d_in[0];
  const int*   ei      = (const int*)d_in[1];
  const int*   batch   = (const int*)d_in[2];
  const float* memory  = (const float*)d_in[3];
  const float* enc_W   = (const float*)d_in[4];
  const float* enc_b   = (const float*)d_in[5];
  const float* gat_W   = (const float*)d_in[6];   // [NL,128,1024]
  const float* att_src = (const float*)d_in[7];
  const float* att_dst = (const float*)d_in[8];
  const float* gat_b   = (const float*)d_in[9];
  const float* W_ih    = (const float*)d_in[10];
  const float* W_hh    = (const float*)d_in[11];
  const float* b_ih    = (const float*)d_in[12];
  const float* b_hh    = (const float*)d_in[13];
  const float* c1W     = (const float*)d_in[14];
  const float* c1b     = (const float*)d_in[15];
  const float* c2W     = (const float*)d_in[16];
  const float* c2b     = (const float*)d_in[17];

  const int N = in_sizes[0] / HIDC;
  const int E = in_sizes[1] / 2;
  const int EN = E + N;
  const int NB = (N + 1023) / 1024;

  char* ws = (char*)d_ws;
  size_t off = 0;
  auto alloc = [&](size_t bytes) -> void* {
    void* p = ws + off;
    off += (bytes + 255) & ~(size_t)255;
    return p;
  };
  unsigned short* hb0 = (unsigned short*)alloc((size_t)N * HIDC * 2);
  unsigned short* hb1 = (unsigned short*)alloc((size_t)N * HIDC * 2);
  unsigned short* agg = (unsigned short*)alloc((size_t)N * 1024 * 2);
  float* aS     = (float*)alloc((size_t)N * NHEAD * 4);
  float* aD     = (float*)alloc((size_t)N * NHEAD * 4);
  short* encT   = (short*)alloc((size_t)128 * 128 * 2);
  short* Wp     = (short*)alloc((size_t)NLAY * 131072 * 2);
  float* waSD   = (float*)alloc((size_t)NLAY * 2048 * 4);
  short* Bt512  = (short*)alloc((size_t)512 * 256 * 2);
  int*   rowptr = (int*)alloc((size_t)(N + 1) * 4);
  size_t zoff0 = off;
  int*   cursor = (int*)alloc((size_t)N * 4);
  int*   degtmp = (int*)alloc((size_t)N * 4);
  size_t zbytes = off - zoff0;
  int*   bsum   = (int*)alloc(64 * 4);
  int*   csr    = (int*)alloc((size_t)EN * 4);
  float* cntbuf = (float*)alloc(64 * 4);

  float* out_logits = (float*)d_out;
  float* out_pooled = (float*)d_out + NGRAPH * NCLS;
  float* out_preds  = (float*)d_out + NGRAPH * NCLS + NGRAPH * HIDC;

  hipMemsetAsync(cursor, 0, zbytes, stream);

  // fused prep: weights (fragment-order B) + d_out/cnt zeroing (one dispatch)
  {
    int total = 16384 + NLAY * 131072 + 512 * 256 + (out_size + 64) + NLAY * 2048;
    prep_kernel<<<(total + 255) / 256, 256, 0, stream>>>(
        enc_W, encT, gat_W, Wp, W_ih, W_hh, Bt512, att_src, att_dst, waSD,
        (float*)d_out, out_size, cntbuf);
  }

  // CSR build
  hist_kernel<<<(EN + 255) / 256, 256, 0, stream>>>(ei, degtmp, E, N);
  scan1_kernel<<<NB, 1024, 0, stream>>>(degtmp, rowptr, bsum, N);
  scan2_kernel<<<1, 64, 0, stream>>>(bsum, NB);
  scatter_kernel<<<(EN + 255) / 256, 256, 0, stream>>>(ei, rowptr, bsum, cursor,
                                                       csr, E, N);

  const int MB = (N + 127) / 128;

  // encoder: hb0 = bf16(relu(x @ enc_W + enc_b)) + fused alphas for layer 0
  mm_gat<<<MB, 512, 0, stream>>>(nullptr, x, encT, enc_b, hb0,
                                 waSD, aS, aD, N, 128, 1);

  unsigned short* hbcur = hb0;
  unsigned short* hbnxt = hb1;
  for (int l = 0; l < NLAY; ++l) {
    gat_agg6<<<(N + 3) / 4, 256, 0, stream>>>(hbcur, rowptr, bsum, csr, aS, aD,
                                              agg, N, EN);
    const float* wnext = (l < NLAY - 1) ? (waSD + (size_t)(l + 1) * 2048) : nullptr;
    mm_gat<<<MB, 512, 0, stream>>>(agg, nullptr, Wp + (size_t)l * 131072,
                                   gat_b + (size_t)l * HIDC, hbnxt,
                                   wnext, aS, aD, N, 1024, (l < NLAY - 1) ? 1 : 0);
    unsigned short* tb = hbcur; hbcur = hbnxt; hbnxt = tb;
  }

  // fused GRU: matmul + gates + blend + mean-pool in one dispatch
  gru_fused<<<(N + 63) / 64, 512, 0, stream>>>(hbcur, memory, Bt512, b_ih, b_hh,
                                               batch, out_pooled, cntbuf, N);

  // classifier
  classifier_kernel<<<NGRAPH, 64, 0, stream>>>(out_pooled, cntbuf, c1W, c1b, c2W, c2b,
                                               out_logits, out_preds);
}